// Round 1
// 823.827 us; speedup vs baseline: 1.3640x; 1.3640x over previous
//
#include <hip/hip_runtime.h>

// Problem constants (fixed by setup_inputs): x (4, 64, 8192, 1) fp32, k=9, dilation=1
#define BB 4
#define DD 64
#define NN 8192
#define KK 9

// ---------------------------------------------------------------------------
// NEW PATH (MFMA filter + exact rescan)
//   K1 knorm2: normalize, emit fp32 xnT, sq, and bf16 hi/lo splits:
//              P = split(xn) (B-operand role), S = split(-2*xn) (A-operand role)
//   K2 kmin:   MFMA bf16-split GEMM computing per-(row, 16-j-group) min of -2*dot
//   K3 ksel:   per row: theta = 9th-smallest group-min (+delta), exact fp32
//              rescan of candidate groups with the previously-verified
//              dot + packed-u64 top-9 code; writes edge_index directly.
// Fallback to the previous (verified, 1124us) path if ws_size is too small.
// ---------------------------------------------------------------------------

typedef __attribute__((ext_vector_type(8))) __bf16 bf16x8;   // 4 VGPR MFMA operand
typedef __attribute__((ext_vector_type(16))) float f32x16;   // 32x32 accumulator

__device__ __forceinline__ unsigned bf16rne(float f) {
    unsigned u = __float_as_uint(f);
    unsigned r = u + 0x7FFFu + ((u >> 16) & 1u);   // round-to-nearest-even
    return r >> 16;
}

__device__ __forceinline__ uint4 pack8(const unsigned* w) {
    return make_uint4(w[0] | (w[1] << 16), w[2] | (w[3] << 16),
                      w[4] | (w[5] << 16), w[6] | (w[7] << 16));
}

// ---------------- K1: normalize + fp32 pack + sq + bf16 hi/lo splits ----------
__global__ __launch_bounds__(256) void knorm2_kernel(const float* __restrict__ x,
                                                     float* __restrict__ xnT,
                                                     float* __restrict__ sq,
                                                     unsigned short* __restrict__ Phi,
                                                     unsigned short* __restrict__ Plo,
                                                     unsigned short* __restrict__ Shi,
                                                     unsigned short* __restrict__ Slo) {
    int t = blockIdx.x * 256 + threadIdx.x;      // row id 0..B*N-1
    int b = t >> 13;
    int n = t & (NN - 1);
    const float* xb = x + (size_t)b * DD * NN + n;
    float v[DD];
    float ss = 0.0f;
#pragma unroll
    for (int d = 0; d < DD; ++d) {
        v[d] = xb[(size_t)d * NN];
        ss = fmaf(v[d], v[d], ss);
    }
    float inv = 1.0f / fmaxf(sqrtf(ss), 1e-12f);
    float s2 = 0.0f;
#pragma unroll
    for (int d = 0; d < DD; ++d) {
        v[d] *= inv;
        s2 = fmaf(v[d], v[d], s2);
    }
    sq[t] = s2;
    float4* o4 = reinterpret_cast<float4*>(xnT + (size_t)t * DD);
#pragma unroll
    for (int d = 0; d < DD; d += 4) o4[d >> 2] = make_float4(v[d], v[d+1], v[d+2], v[d+3]);

    size_t base = (size_t)t * DD;
#pragma unroll
    for (int d0 = 0; d0 < DD; d0 += 8) {
        unsigned ph[8], pl[8], sh[8], sl[8];
#pragma unroll
        for (int e = 0; e < 8; ++e) {
            float f = v[d0 + e];
            unsigned hb = bf16rne(f);
            float lo = f - __uint_as_float(hb << 16);
            ph[e] = hb;
            pl[e] = bf16rne(lo);
            float g = -2.0f * f;                     // exact scale
            unsigned gh = bf16rne(g);
            float glo = g - __uint_as_float(gh << 16);
            sh[e] = gh;
            sl[e] = bf16rne(glo);
        }
        *reinterpret_cast<uint4*>(Phi + base + d0) = pack8(ph);
        *reinterpret_cast<uint4*>(Plo + base + d0) = pack8(pl);
        *reinterpret_cast<uint4*>(Shi + base + d0) = pack8(sh);
        *reinterpret_cast<uint4*>(Slo + base + d0) = pack8(sl);
    }
}

// ---------------- K2: MFMA min pass -----------------------------------------
// Wave = 32 i-rows; block = 4 waves = 128 rows; grid (256 rowblocks, 4 jsplits).
// D[jj][ii] = sum_k (-2 x_j)[k] * (x_i)[k] via 3 bf16-split terms (drop lo*lo,
// |err| <= ~1.5e-5). C/D col = lane&31 (HW-verified m74/m101) -> each lane's 16
// values belong to one i-row; min them and store minbuf[group][row], where
// group = 2*tile + (lane>>5) is a known 16-j subset: jj = 8q + 4*(lane>>5) + r
// (verified C-row formula). k-slot map is applied identically to A and B, so
// any internal k-permutation cancels (dot is k-permutation invariant).
__global__ __launch_bounds__(256, 4) void kmin_kernel(const unsigned short* __restrict__ Shi,
                                                      const unsigned short* __restrict__ Slo,
                                                      const unsigned short* __restrict__ Phi,
                                                      const unsigned short* __restrict__ Plo,
                                                      float* __restrict__ minbuf) {
    const int lane = threadIdx.x & 63;
    const int wave = threadIdx.x >> 6;
    const int l31 = lane & 31;
    const int half = lane >> 5;
    const int i0 = blockIdx.x * 128 + wave * 32;        // global i-row base
    const int b = i0 >> 13;
    const int jloc0 = blockIdx.y * (NN / 4);            // batch-local j start

    bf16x8 Bh[4], Bl[4];
    {
        const size_t ib = (size_t)(i0 + l31) * DD + half * 8;
#pragma unroll
        for (int kc = 0; kc < 4; ++kc) {
            Bh[kc] = *reinterpret_cast<const bf16x8*>(Phi + ib + kc * 16);
            Bl[kc] = *reinterpret_cast<const bf16x8*>(Plo + ib + kc * 16);
        }
    }
    const size_t ja0 = ((size_t)b * NN + jloc0 + l31) * DD + half * 8;
    float* mb = minbuf + (size_t)(i0 + l31);

#pragma unroll 1
    for (int tt = 0; tt < NN / 4 / 32; ++tt) {          // 64 tiles of 32 j
        const size_t ja = ja0 + (size_t)tt * 32 * DD;
        bf16x8 Ah[4], Al[4];
#pragma unroll
        for (int kc = 0; kc < 4; ++kc) {
            Ah[kc] = *reinterpret_cast<const bf16x8*>(Shi + ja + kc * 16);
            Al[kc] = *reinterpret_cast<const bf16x8*>(Slo + ja + kc * 16);
        }
        f32x16 c = {};
#pragma unroll
        for (int kc = 0; kc < 4; ++kc)
            c = __builtin_amdgcn_mfma_f32_32x32x16_bf16(Ah[kc], Bh[kc], c, 0, 0, 0);
#pragma unroll
        for (int kc = 0; kc < 4; ++kc)
            c = __builtin_amdgcn_mfma_f32_32x32x16_bf16(Ah[kc], Bl[kc], c, 0, 0, 0);
#pragma unroll
        for (int kc = 0; kc < 4; ++kc)
            c = __builtin_amdgcn_mfma_f32_32x32x16_bf16(Al[kc], Bh[kc], c, 0, 0, 0);
        float m0 = fminf(fminf(c[0], c[1]), fminf(c[2], c[3]));
        float m1 = fminf(fminf(c[4], c[5]), fminf(c[6], c[7]));
        float m2 = fminf(fminf(c[8], c[9]), fminf(c[10], c[11]));
        float m3 = fminf(fminf(c[12], c[13]), fminf(c[14], c[15]));
        float m = fminf(fminf(m0, m1), fminf(m2, m3));
        int g = ((jloc0 >> 5) + tt) * 2 + half;         // batch-local group id 0..511
        mb[(size_t)g * (BB * NN)] = m;
    }
}

// ---------------- K3: threshold + candidate list + exact fp32 rescan ---------
// One thread per row. theta = 9th-smallest group-min + delta; delta=1e-3 covers
// bf16-split error (~1.5e-5), sq_j deviation from 1 (~1.2e-7) and fp32-vs-MFMA
// cross error; completeness: any top-9 element's group has min <= v9 <= theta.
// Candidate groups go to a per-thread LDS list so the heavy loop is per-lane
// compact (no wave-wide divergence blowup). Rescan math is byte-identical to
// the previously-verified kdist kernel -> identical ordering/tie-breaking.
__global__ __launch_bounds__(256) void ksel_kernel(const float* __restrict__ xnT,
                                                   const float* __restrict__ sq,
                                                   const float* __restrict__ minbuf,
                                                   int* __restrict__ out) {
    __shared__ unsigned short glist[256 * 24];
    const int tid = threadIdx.x;
    const int t = blockIdx.x * 256 + tid;
    const int b = t >> 13;
    const int n = t & (NN - 1);
    const float* __restrict__ mrow = minbuf + t;

    // phase a: 9 smallest group-mins (branchless sorted-insert network)
    float th[KK];
#pragma unroll
    for (int m = 0; m < KK; ++m) th[m] = __uint_as_float(0x7f800000u);
#pragma unroll 8
    for (int g = 0; g < 2 * (NN / 32); ++g) {           // 512 groups
        float m = mrow[(size_t)g * (BB * NN)];
#pragma unroll
        for (int q = 0; q < KK; ++q) {
            float lo = fminf(th[q], m);
            float hi = fmaxf(th[q], m);
            th[q] = lo;
            m = hi;
        }
    }
    const float theta = th[KK - 1] + 1e-3f;

    // phase b: collect candidate groups (min <= theta). cnt>=9 by construction.
    int cnt = 0;
    unsigned short* gl = glist + tid * 24;
#pragma unroll 8
    for (int g = 0; g < 2 * (NN / 32); ++g) {
        float m = mrow[(size_t)g * (BB * NN)];
        if (m <= theta) {
            if (cnt < 24) gl[cnt] = (unsigned short)g;
            ++cnt;
        }
    }
    const bool ovf = (cnt > 24);                        // ~impossible; rigor fallback
    const int ng = ovf ? 2 * (NN / 32) : cnt;

    // row point in registers (same pattern as the verified kernel)
    const float* __restrict__ Bb = xnT + (size_t)b * NN * DD;
    const float* __restrict__ sqb = sq + (size_t)b * NN;
    float ar[DD];
    {
        const float4* a4 = reinterpret_cast<const float4*>(Bb + (size_t)n * DD);
#pragma unroll
        for (int d = 0; d < DD; d += 4) {
            float4 f = a4[d >> 2];
            ar[d] = f.x; ar[d + 1] = f.y; ar[d + 2] = f.z; ar[d + 3] = f.w;
        }
    }
#pragma unroll
    for (int d = 0; d < DD; ++d) asm volatile("" : "+v"(ar[d]));

    unsigned long long kd[KK];
#pragma unroll
    for (int m = 0; m < KK; ++m) kd[m] = ~0ULL;

#pragma unroll 1
    for (int ci = 0; ci < ng; ++ci) {
        int g = ovf ? ci : (int)gl[ci];
        int jb = (g >> 1) * 32 + (g & 1) * 4;           // group -> 16 j's: jb + 8q + r
#pragma unroll 1
        for (int q = 0; q < 4; ++q) {
#pragma unroll
            for (int r = 0; r < 4; ++r) {
                int j = jb + q * 8 + r;
                const float4* bc4 = reinterpret_cast<const float4*>(Bb + (size_t)j * DD);
                float a0 = 0.0f, a1 = 0.0f, a2 = 0.0f, a3 = 0.0f;
#pragma unroll
                for (int d4 = 0; d4 < DD / 4; ++d4) {
                    float4 f = bc4[d4];
                    a0 = fmaf(ar[4 * d4 + 0], f.x, a0);
                    a1 = fmaf(ar[4 * d4 + 1], f.y, a1);
                    a2 = fmaf(ar[4 * d4 + 2], f.z, a2);
                    a3 = fmaf(ar[4 * d4 + 3], f.w, a3);
                }
                float dot = (a0 + a1) + (a2 + a3);
                float key = fmaf(-2.0f, dot, sqb[j]);
                unsigned ub = __float_as_uint(key);
                ub ^= (0x80000000u | (unsigned)((int)ub >> 31));
                unsigned long long cnd = ((unsigned long long)ub << 32) | (unsigned)j;
                if (cnd < kd[KK - 1]) {
#pragma unroll
                    for (int m = 0; m < KK; ++m) {
                        bool sw = cnd < kd[m];
                        unsigned long long lo = sw ? cnd : kd[m];
                        unsigned long long hi = sw ? kd[m] : cnd;
                        kd[m] = lo;
                        cnd = hi;
                    }
                }
            }
        }
    }
    int* out0 = out + (size_t)t * KK;
    int* out1 = out + (size_t)BB * NN * KK + (size_t)t * KK;
#pragma unroll
    for (int m = 0; m < KK; ++m) {
        out0[m] = (int)(kd[m] & 0xFFFFFFFFULL);
        out1[m] = n;
    }
}

// ===========================================================================
// OLD PATH (verified fallback, 1124us) -- unchanged
// ===========================================================================
__global__ __launch_bounds__(256) void knorm_kernel(const float* __restrict__ x,
                                                    float* __restrict__ xnT,
                                                    float* __restrict__ sq) {
    int t = blockIdx.x * 256 + threadIdx.x;
    int b = t >> 13;
    int n = t & (NN - 1);
    const float* xb = x + (size_t)b * DD * NN + n;
    float v[DD];
    float ss = 0.0f;
#pragma unroll
    for (int d = 0; d < DD; ++d) {
        v[d] = xb[(size_t)d * NN];
        ss = fmaf(v[d], v[d], ss);
    }
    float norm = sqrtf(ss);
    float inv = 1.0f / fmaxf(norm, 1e-12f);
    float s2 = 0.0f;
#pragma unroll
    for (int d = 0; d < DD; ++d) {
        float xv = v[d] * inv;
        v[d] = xv;
        s2 = fmaf(xv, xv, s2);
    }
    float4* o4 = reinterpret_cast<float4*>(xnT + (size_t)t * DD);
#pragma unroll
    for (int d = 0; d < DD; d += 4) {
        o4[d >> 2] = make_float4(v[d], v[d + 1], v[d + 2], v[d + 3]);
    }
    sq[t] = s2;
}

template <int S>
__global__ __launch_bounds__(256, 2) void kdist_kernel(const float* __restrict__ xnT,
                                                       const float* __restrict__ sq,
                                                       unsigned long long* __restrict__ cand) {
    const int rb = blockIdx.x;
    const int b = rb >> 5;
    const int nbase = (rb & 31) * 256;
    const int n = nbase + threadIdx.x;
    const int s = blockIdx.y;
    const int jcount = NN / S;
    const int j0 = s * jcount;
    const int j1 = j0 + jcount;

    const float* __restrict__ Bb = xnT + ((size_t)b * NN) * DD;
    const float* __restrict__ sqb = sq + (size_t)b * NN;

    float ar[DD];
    {
        const float4* a4 = reinterpret_cast<const float4*>(Bb + (size_t)n * DD);
#pragma unroll
        for (int d = 0; d < DD; d += 4) {
            float4 f = a4[d >> 2];
            ar[d] = f.x; ar[d + 1] = f.y; ar[d + 2] = f.z; ar[d + 3] = f.w;
        }
    }
#pragma unroll
    for (int d = 0; d < DD; ++d) {
        asm volatile("" : "+v"(ar[d]));
    }

    unsigned long long kd[KK];
#pragma unroll
    for (int m = 0; m < KK; ++m) kd[m] = ~0ULL;

#pragma unroll 2
    for (int j = j0; j < j1; ++j) {
        const float4* bc4 = reinterpret_cast<const float4*>(Bb + (size_t)j * DD);
        float a0 = 0.0f, a1 = 0.0f, a2 = 0.0f, a3 = 0.0f;
#pragma unroll
        for (int d4 = 0; d4 < DD / 4; ++d4) {
            float4 f = bc4[d4];
            a0 = fmaf(ar[4 * d4 + 0], f.x, a0);
            a1 = fmaf(ar[4 * d4 + 1], f.y, a1);
            a2 = fmaf(ar[4 * d4 + 2], f.z, a2);
            a3 = fmaf(ar[4 * d4 + 3], f.w, a3);
        }
        float dot = (a0 + a1) + (a2 + a3);
        float key = fmaf(-2.0f, dot, sqb[j]);
        unsigned int ub = __float_as_uint(key);
        ub ^= (0x80000000u | (unsigned int)((int)ub >> 31));
        unsigned long long cnd = ((unsigned long long)ub << 32) | (unsigned int)j;
        if (cnd < kd[KK - 1]) {
#pragma unroll
            for (int m = 0; m < KK; ++m) {
                bool sw = cnd < kd[m];
                unsigned long long lo = sw ? cnd : kd[m];
                unsigned long long hi = sw ? kd[m] : cnd;
                kd[m] = lo;
                cnd = hi;
            }
        }
    }

    unsigned long long* outc = cand + ((size_t)(b * NN + n) * S + s) * KK;
#pragma unroll
    for (int m = 0; m < KK; ++m) outc[m] = kd[m];
}

template <int S>
__global__ __launch_bounds__(256) void kmerge_kernel(const unsigned long long* __restrict__ cand,
                                                     int* __restrict__ out) {
    int t = blockIdx.x * 256 + threadIdx.x;
    const unsigned long long* c = cand + (size_t)t * (S * KK);
    unsigned long long kd[KK];
#pragma unroll
    for (int m = 0; m < KK; ++m) kd[m] = ~0ULL;
#pragma unroll
    for (int q = 0; q < S * KK; ++q) {
        unsigned long long cnd = c[q];
        if (cnd < kd[KK - 1]) {
#pragma unroll
            for (int m = 0; m < KK; ++m) {
                bool sw = cnd < kd[m];
                unsigned long long lo = sw ? cnd : kd[m];
                unsigned long long hi = sw ? kd[m] : cnd;
                kd[m] = lo;
                cnd = hi;
            }
        }
    }
    int n = t & (NN - 1);
    int* out0 = out + (size_t)t * KK;
    int* out1 = out + (size_t)BB * NN * KK + (size_t)t * KK;
#pragma unroll
    for (int m = 0; m < KK; ++m) {
        out0[m] = (int)(kd[m] & 0xFFFFFFFFULL);
        out1[m] = n;
    }
}

extern "C" void kernel_launch(void* const* d_in, const int* in_sizes, int n_in,
                              void* d_out, int out_size, void* d_ws, size_t ws_size,
                              hipStream_t stream) {
    const float* x = (const float*)d_in[0];
    int* out = (int*)d_out;
    char* ws = (char*)d_ws;

    // Shared layout head
    constexpr size_t XNT_B = (size_t)BB * NN * DD * 4;          //  8,388,608
    constexpr size_t SQ_B  = (size_t)BB * NN * 4;               //    131,072
    float* xnT = (float*)ws;
    float* sq  = (float*)(ws + XNT_B);

    // New-path layout
    constexpr size_t BF_B  = (size_t)BB * NN * DD * 2;          //  4,194,304 each
    constexpr size_t OFF_PHI = XNT_B + SQ_B;
    constexpr size_t OFF_PLO = OFF_PHI + BF_B;
    constexpr size_t OFF_SHI = OFF_PLO + BF_B;
    constexpr size_t OFF_SLO = OFF_SHI + BF_B;
    constexpr size_t OFF_MIN = OFF_SLO + BF_B;
    constexpr size_t MIN_B   = (size_t)512 * BB * NN * 4;       // 67,108,864
    constexpr size_t NEED_NEW = OFF_MIN + MIN_B;                // 92,405,760

    if (ws_size >= NEED_NEW) {
        unsigned short* Phi = (unsigned short*)(ws + OFF_PHI);
        unsigned short* Plo = (unsigned short*)(ws + OFF_PLO);
        unsigned short* Shi = (unsigned short*)(ws + OFF_SHI);
        unsigned short* Slo = (unsigned short*)(ws + OFF_SLO);
        float* minbuf = (float*)(ws + OFF_MIN);

        knorm2_kernel<<<dim3(BB * NN / 256), dim3(256), 0, stream>>>(x, xnT, sq, Phi, Plo, Shi, Slo);
        kmin_kernel<<<dim3(BB * NN / 128, 4), dim3(256), 0, stream>>>(Shi, Slo, Phi, Plo, minbuf);
        ksel_kernel<<<dim3(BB * NN / 256), dim3(256), 0, stream>>>(xnT, sq, minbuf, out);
        return;
    }

    // Old verified path
    unsigned long long* cand = (unsigned long long*)(ws + XNT_B + SQ_B);
    const size_t base = XNT_B + SQ_B;
    const size_t need8 = base + (size_t)BB * NN * 8 * KK * 8;

    knorm_kernel<<<dim3(BB * NN / 256), dim3(256), 0, stream>>>(x, xnT, sq);
    if (ws_size >= need8) {
        kdist_kernel<8><<<dim3(BB * NN / 256, 8), dim3(256), 0, stream>>>(xnT, sq, cand);
        kmerge_kernel<8><<<dim3(BB * NN / 256), dim3(256), 0, stream>>>(cand, out);
    } else {
        kdist_kernel<4><<<dim3(BB * NN / 256, 4), dim3(256), 0, stream>>>(xnT, sq, cand);
        kmerge_kernel<4><<<dim3(BB * NN / 256), dim3(256), 0, stream>>>(cand, out);
    }
}

// Round 2
// 477.504 us; speedup vs baseline: 2.3533x; 1.7253x over previous
//
#include <hip/hip_runtime.h>

// Problem constants (fixed by setup_inputs): x (4, 64, 8192, 1) fp32, k=9, dilation=1
#define BB 4
#define DD 64
#define NN 8192
#define KK 9

// ---------------------------------------------------------------------------
// MFMA filter + exact rescan
//   K1 knorm2: normalize, emit fp32 xnT, sq, bf16 hi/lo splits
//   K2 kmin:   MFMA bf16-split GEMM -> per-(row, 16-j-group) min of -2*dot,
//              stored ROW-MAJOR: minbuf[row*512 + g], g = half*256 + tile
//   K3 ksel:   wave-per-row: theta = 9th-smallest group-min (+1e-3), ballot-
//              compacted candidate list, lane-balanced exact fp32 rescan,
//              cross-lane top-9 merge. Writes edge_index directly.
// Fallback to the original verified path if ws_size is too small.
// ---------------------------------------------------------------------------

typedef __attribute__((ext_vector_type(8))) __bf16 bf16x8;   // 4 VGPR MFMA operand
typedef __attribute__((ext_vector_type(16))) float f32x16;   // 32x32 accumulator

__device__ __forceinline__ unsigned bf16rne(float f) {
    unsigned u = __float_as_uint(f);
    unsigned r = u + 0x7FFFu + ((u >> 16) & 1u);   // round-to-nearest-even
    return r >> 16;
}

__device__ __forceinline__ uint4 pack8(const unsigned* w) {
    return make_uint4(w[0] | (w[1] << 16), w[2] | (w[3] << 16),
                      w[4] | (w[5] << 16), w[6] | (w[7] << 16));
}

// ---------------- K1: normalize + fp32 pack + sq + bf16 hi/lo splits ----------
__global__ __launch_bounds__(256) void knorm2_kernel(const float* __restrict__ x,
                                                     float* __restrict__ xnT,
                                                     float* __restrict__ sq,
                                                     unsigned short* __restrict__ Phi,
                                                     unsigned short* __restrict__ Plo,
                                                     unsigned short* __restrict__ Shi,
                                                     unsigned short* __restrict__ Slo) {
    int t = blockIdx.x * 256 + threadIdx.x;      // row id 0..B*N-1
    int b = t >> 13;
    int n = t & (NN - 1);
    const float* xb = x + (size_t)b * DD * NN + n;
    float v[DD];
    float ss = 0.0f;
#pragma unroll
    for (int d = 0; d < DD; ++d) {
        v[d] = xb[(size_t)d * NN];
        ss = fmaf(v[d], v[d], ss);
    }
    float inv = 1.0f / fmaxf(sqrtf(ss), 1e-12f);
    float s2 = 0.0f;
#pragma unroll
    for (int d = 0; d < DD; ++d) {
        v[d] *= inv;
        s2 = fmaf(v[d], v[d], s2);
    }
    sq[t] = s2;
    float4* o4 = reinterpret_cast<float4*>(xnT + (size_t)t * DD);
#pragma unroll
    for (int d = 0; d < DD; d += 4) o4[d >> 2] = make_float4(v[d], v[d+1], v[d+2], v[d+3]);

    size_t base = (size_t)t * DD;
#pragma unroll
    for (int d0 = 0; d0 < DD; d0 += 8) {
        unsigned ph[8], pl[8], sh[8], sl[8];
#pragma unroll
        for (int e = 0; e < 8; ++e) {
            float f = v[d0 + e];
            unsigned hb = bf16rne(f);
            float lo = f - __uint_as_float(hb << 16);
            ph[e] = hb;
            pl[e] = bf16rne(lo);
            float g = -2.0f * f;                     // exact scale
            unsigned gh = bf16rne(g);
            float glo = g - __uint_as_float(gh << 16);
            sh[e] = gh;
            sl[e] = bf16rne(glo);
        }
        *reinterpret_cast<uint4*>(Phi + base + d0) = pack8(ph);
        *reinterpret_cast<uint4*>(Plo + base + d0) = pack8(pl);
        *reinterpret_cast<uint4*>(Shi + base + d0) = pack8(sh);
        *reinterpret_cast<uint4*>(Slo + base + d0) = pack8(sl);
    }
}

// ---------------- K2: MFMA min pass -----------------------------------------
// Wave = 32 i-rows; block = 4 waves = 128 rows; grid (256 rowblocks, 4 jsplits).
// C/D col = lane&31 (HW-verified); C-row = (reg&3) + 8*(reg>>2) + 4*half.
// Group id g = half*256 + T (T = global 32-j tile), so each lane's successive
// tiles produce CONSECUTIVE g -> batched float4 row-major writes:
//   minbuf[row*512 + g],  j(g, s) = (g&255)*32 + (s>>2)*8 + (g>>8)*4 + (s&3)
__global__ __launch_bounds__(256, 4) void kmin_kernel(const unsigned short* __restrict__ Shi,
                                                      const unsigned short* __restrict__ Slo,
                                                      const unsigned short* __restrict__ Phi,
                                                      const unsigned short* __restrict__ Plo,
                                                      float* __restrict__ minbuf) {
    const int lane = threadIdx.x & 63;
    const int wave = threadIdx.x >> 6;
    const int l31 = lane & 31;
    const int half = lane >> 5;
    const int i0 = blockIdx.x * 128 + wave * 32;        // global i-row base
    const int b = i0 >> 13;
    const int jloc0 = blockIdx.y * (NN / 4);            // batch-local j start
    const int goff = jloc0 >> 5;                        // tile base (64 per split)
    const int row = i0 + l31;                           // global row this lane owns

    bf16x8 Bh[4], Bl[4];
    {
        const size_t ib = (size_t)row * DD + half * 8;
#pragma unroll
        for (int kc = 0; kc < 4; ++kc) {
            Bh[kc] = *reinterpret_cast<const bf16x8*>(Phi + ib + kc * 16);
            Bl[kc] = *reinterpret_cast<const bf16x8*>(Plo + ib + kc * 16);
        }
    }
    const size_t ja0 = ((size_t)b * NN + jloc0 + l31) * DD + half * 8;

#pragma unroll 1
    for (int t4 = 0; t4 < 16; ++t4) {                   // 16 batches x 4 tiles
        float mins[4];
#pragma unroll
        for (int u = 0; u < 4; ++u) {
            const int tt = t4 * 4 + u;
            const size_t ja = ja0 + (size_t)tt * 32 * DD;
            bf16x8 Ah[4], Al[4];
#pragma unroll
            for (int kc = 0; kc < 4; ++kc) {
                Ah[kc] = *reinterpret_cast<const bf16x8*>(Shi + ja + kc * 16);
                Al[kc] = *reinterpret_cast<const bf16x8*>(Slo + ja + kc * 16);
            }
            f32x16 c = {};
#pragma unroll
            for (int kc = 0; kc < 4; ++kc)
                c = __builtin_amdgcn_mfma_f32_32x32x16_bf16(Ah[kc], Bh[kc], c, 0, 0, 0);
#pragma unroll
            for (int kc = 0; kc < 4; ++kc)
                c = __builtin_amdgcn_mfma_f32_32x32x16_bf16(Ah[kc], Bl[kc], c, 0, 0, 0);
#pragma unroll
            for (int kc = 0; kc < 4; ++kc)
                c = __builtin_amdgcn_mfma_f32_32x32x16_bf16(Al[kc], Bh[kc], c, 0, 0, 0);
            float m0 = fminf(fminf(c[0], c[1]), fminf(c[2], c[3]));
            float m1 = fminf(fminf(c[4], c[5]), fminf(c[6], c[7]));
            float m2 = fminf(fminf(c[8], c[9]), fminf(c[10], c[11]));
            float m3 = fminf(fminf(c[12], c[13]), fminf(c[14], c[15]));
            mins[u] = fminf(fminf(m0, m1), fminf(m2, m3));
        }
        float4* dst = reinterpret_cast<float4*>(minbuf + (size_t)row * 512 +
                                                half * 256 + goff + t4 * 4);
        *dst = make_float4(mins[0], mins[1], mins[2], mins[3]);
    }
}

// ---------------- K3: wave-per-row threshold + balanced exact rescan ---------
// One WAVE per row; grid = B*N/4 blocks of 4 waves. Lane l owns groups
// g = l*8 .. l*8+7 (two coalesced float4 loads). theta via 9 rounds of
// wave-min extraction (duplicate-consumption only raises theta -> safe;
// completeness: the 9 smallest group-mins are 9 distinct groups each holding
// an exact key <= th9+err => v9 <= th9+err => every top-9's group-min <=
// v9+err <= th9+2err << th9+1e-3). Candidates ballot-compacted to LDS, j-work
// distributed round-robin over 64 lanes; exact fp32 dot identical to the
// verified kernel; u64-keyed cross-lane top-9 extraction (keys unique: j in
// low bits -> exactly one lane pops per round).
__global__ __launch_bounds__(256) void ksel_kernel(const float* __restrict__ xnT,
                                                   const float* __restrict__ sq,
                                                   const float* __restrict__ minbuf,
                                                   int* __restrict__ out) {
    __shared__ unsigned short glist[4][40];
    const int lane = threadIdx.x & 63;
    const int wave = threadIdx.x >> 6;
    const int t = blockIdx.x * 4 + wave;                 // row id
    const int tu = __builtin_amdgcn_readfirstlane(t);    // wave-uniform row
    const int b = tu >> 13;
    const int n = tu & (NN - 1);

    // lane's 8 group-mins (coalesced: 2KB contiguous per wave)
    float gm[8];
    {
        const float4* m4 = reinterpret_cast<const float4*>(minbuf + (size_t)tu * 512 + lane * 8);
        float4 a = m4[0], c = m4[1];
        gm[0] = a.x; gm[1] = a.y; gm[2] = a.z; gm[3] = a.w;
        gm[4] = c.x; gm[5] = c.y; gm[6] = c.z; gm[7] = c.w;
    }

    // theta: 9 rounds of wave-min extraction
    float w[8];
#pragma unroll
    for (int q = 0; q < 8; ++q) w[q] = gm[q];
    float th9 = 0.0f;
#pragma unroll
    for (int r = 0; r < KK; ++r) {
        float lm = fminf(fminf(fminf(w[0], w[1]), fminf(w[2], w[3])),
                         fminf(fminf(w[4], w[5]), fminf(w[6], w[7])));
        float wm = lm;
#pragma unroll
        for (int d = 1; d < 64; d <<= 1) wm = fminf(wm, __shfl_xor(wm, d));
#pragma unroll
        for (int q = 0; q < 8; ++q) if (w[q] <= wm) w[q] = __uint_as_float(0x7f800000u);
        th9 = wm;
    }
    const float theta = th9 + 1e-3f;

    // ballot-compact candidate groups into LDS list
    int cnt = 0;
    unsigned short* gl = &glist[wave][0];
#pragma unroll
    for (int q = 0; q < 8; ++q) {
        bool c = gm[q] <= theta;
        unsigned long long mask = __ballot(c);
        int pos = cnt + __popcll(mask & ((1ULL << lane) - 1ULL));
        if (c && pos < 40) gl[pos] = (unsigned short)(lane * 8 + q);
        cnt += __popcll(mask);
    }
    __syncthreads();

    // row vector (wave-uniform address -> scalar loads)
    const float* __restrict__ Bb = xnT + (size_t)b * NN * DD;
    const float* __restrict__ sqb = sq + (size_t)b * NN;
    float ar[DD];
    {
        const float4* a4 = reinterpret_cast<const float4*>(xnT + (size_t)tu * DD);
#pragma unroll
        for (int d = 0; d < DD; d += 4) {
            float4 f = a4[d >> 2];
            ar[d] = f.x; ar[d + 1] = f.y; ar[d + 2] = f.z; ar[d + 3] = f.w;
        }
    }

    unsigned long long kd[KK];
#pragma unroll
    for (int m = 0; m < KK; ++m) kd[m] = ~0ULL;

    const bool ovf = (cnt > 40);
    const int total = ovf ? NN : cnt * 16;
#pragma unroll 1
    for (int idx = lane; idx < total; idx += 64) {
        int j;
        if (ovf) {
            j = idx;
        } else {
            int g = (int)gl[idx >> 4];
            int s4 = idx & 15;
            j = (g & 255) * 32 + ((s4 >> 2) * 8) + ((g >> 8) * 4) + (s4 & 3);
        }
        const float4* bc4 = reinterpret_cast<const float4*>(Bb + (size_t)j * DD);
        float a0 = 0.0f, a1 = 0.0f, a2 = 0.0f, a3 = 0.0f;
#pragma unroll
        for (int d4 = 0; d4 < DD / 4; ++d4) {
            float4 f = bc4[d4];
            a0 = fmaf(ar[4 * d4 + 0], f.x, a0);
            a1 = fmaf(ar[4 * d4 + 1], f.y, a1);
            a2 = fmaf(ar[4 * d4 + 2], f.z, a2);
            a3 = fmaf(ar[4 * d4 + 3], f.w, a3);
        }
        float dot = (a0 + a1) + (a2 + a3);
        float key = fmaf(-2.0f, dot, sqb[j]);
        unsigned ub = __float_as_uint(key);
        ub ^= (0x80000000u | (unsigned)((int)ub >> 31));
        unsigned long long cnd = ((unsigned long long)ub << 32) | (unsigned)j;
        if (cnd < kd[KK - 1]) {
#pragma unroll
            for (int m = 0; m < KK; ++m) {
                bool sw = cnd < kd[m];
                unsigned long long lo = sw ? cnd : kd[m];
                unsigned long long hi = sw ? kd[m] : cnd;
                kd[m] = lo;
                cnd = hi;
            }
        }
    }

    // cross-lane top-9 extraction; lane r keeps rank r
    unsigned long long kout = ~0ULL;
#pragma unroll
    for (int r = 0; r < KK; ++r) {
        unsigned long long c = kd[0];
        unsigned long long wm = c;
#pragma unroll
        for (int d = 1; d < 64; d <<= 1) {
            unsigned long long o = __shfl_xor(wm, d);
            wm = (o < wm) ? o : wm;
        }
        if (lane == r) kout = wm;
        if (c == wm) {
#pragma unroll
            for (int m = 0; m < KK - 1; ++m) kd[m] = kd[m + 1];
            kd[KK - 1] = ~0ULL;
        }
    }

    if (lane < KK) {
        out[(size_t)tu * KK + lane] = (int)(kout & 0xFFFFFFFFULL);
        out[(size_t)BB * NN * KK + (size_t)tu * KK + lane] = n;
    }
}

// ===========================================================================
// OLD PATH (verified fallback) -- unchanged
// ===========================================================================
__global__ __launch_bounds__(256) void knorm_kernel(const float* __restrict__ x,
                                                    float* __restrict__ xnT,
                                                    float* __restrict__ sq) {
    int t = blockIdx.x * 256 + threadIdx.x;
    int b = t >> 13;
    int n = t & (NN - 1);
    const float* xb = x + (size_t)b * DD * NN + n;
    float v[DD];
    float ss = 0.0f;
#pragma unroll
    for (int d = 0; d < DD; ++d) {
        v[d] = xb[(size_t)d * NN];
        ss = fmaf(v[d], v[d], ss);
    }
    float norm = sqrtf(ss);
    float inv = 1.0f / fmaxf(norm, 1e-12f);
    float s2 = 0.0f;
#pragma unroll
    for (int d = 0; d < DD; ++d) {
        float xv = v[d] * inv;
        v[d] = xv;
        s2 = fmaf(xv, xv, s2);
    }
    float4* o4 = reinterpret_cast<float4*>(xnT + (size_t)t * DD);
#pragma unroll
    for (int d = 0; d < DD; d += 4) {
        o4[d >> 2] = make_float4(v[d], v[d + 1], v[d + 2], v[d + 3]);
    }
    sq[t] = s2;
}

template <int S>
__global__ __launch_bounds__(256, 2) void kdist_kernel(const float* __restrict__ xnT,
                                                       const float* __restrict__ sq,
                                                       unsigned long long* __restrict__ cand) {
    const int rb = blockIdx.x;
    const int b = rb >> 5;
    const int nbase = (rb & 31) * 256;
    const int n = nbase + threadIdx.x;
    const int s = blockIdx.y;
    const int jcount = NN / S;
    const int j0 = s * jcount;
    const int j1 = j0 + jcount;

    const float* __restrict__ Bb = xnT + ((size_t)b * NN) * DD;
    const float* __restrict__ sqb = sq + (size_t)b * NN;

    float ar[DD];
    {
        const float4* a4 = reinterpret_cast<const float4*>(Bb + (size_t)n * DD);
#pragma unroll
        for (int d = 0; d < DD; d += 4) {
            float4 f = a4[d >> 2];
            ar[d] = f.x; ar[d + 1] = f.y; ar[d + 2] = f.z; ar[d + 3] = f.w;
        }
    }
#pragma unroll
    for (int d = 0; d < DD; ++d) {
        asm volatile("" : "+v"(ar[d]));
    }

    unsigned long long kd[KK];
#pragma unroll
    for (int m = 0; m < KK; ++m) kd[m] = ~0ULL;

#pragma unroll 2
    for (int j = j0; j < j1; ++j) {
        const float4* bc4 = reinterpret_cast<const float4*>(Bb + (size_t)j * DD);
        float a0 = 0.0f, a1 = 0.0f, a2 = 0.0f, a3 = 0.0f;
#pragma unroll
        for (int d4 = 0; d4 < DD / 4; ++d4) {
            float4 f = bc4[d4];
            a0 = fmaf(ar[4 * d4 + 0], f.x, a0);
            a1 = fmaf(ar[4 * d4 + 1], f.y, a1);
            a2 = fmaf(ar[4 * d4 + 2], f.z, a2);
            a3 = fmaf(ar[4 * d4 + 3], f.w, a3);
        }
        float dot = (a0 + a1) + (a2 + a3);
        float key = fmaf(-2.0f, dot, sqb[j]);
        unsigned int ub = __float_as_uint(key);
        ub ^= (0x80000000u | (unsigned int)((int)ub >> 31));
        unsigned long long cnd = ((unsigned long long)ub << 32) | (unsigned int)j;
        if (cnd < kd[KK - 1]) {
#pragma unroll
            for (int m = 0; m < KK; ++m) {
                bool sw = cnd < kd[m];
                unsigned long long lo = sw ? cnd : kd[m];
                unsigned long long hi = sw ? kd[m] : cnd;
                kd[m] = lo;
                cnd = hi;
            }
        }
    }

    unsigned long long* outc = cand + ((size_t)(b * NN + n) * S + s) * KK;
#pragma unroll
    for (int m = 0; m < KK; ++m) outc[m] = kd[m];
}

template <int S>
__global__ __launch_bounds__(256) void kmerge_kernel(const unsigned long long* __restrict__ cand,
                                                     int* __restrict__ out) {
    int t = blockIdx.x * 256 + threadIdx.x;
    const unsigned long long* c = cand + (size_t)t * (S * KK);
    unsigned long long kd[KK];
#pragma unroll
    for (int m = 0; m < KK; ++m) kd[m] = ~0ULL;
#pragma unroll
    for (int q = 0; q < S * KK; ++q) {
        unsigned long long cnd = c[q];
        if (cnd < kd[KK - 1]) {
#pragma unroll
            for (int m = 0; m < KK; ++m) {
                bool sw = cnd < kd[m];
                unsigned long long lo = sw ? cnd : kd[m];
                unsigned long long hi = sw ? kd[m] : cnd;
                kd[m] = lo;
                cnd = hi;
            }
        }
    }
    int n = t & (NN - 1);
    int* out0 = out + (size_t)t * KK;
    int* out1 = out + (size_t)BB * NN * KK + (size_t)t * KK;
#pragma unroll
    for (int m = 0; m < KK; ++m) {
        out0[m] = (int)(kd[m] & 0xFFFFFFFFULL);
        out1[m] = n;
    }
}

extern "C" void kernel_launch(void* const* d_in, const int* in_sizes, int n_in,
                              void* d_out, int out_size, void* d_ws, size_t ws_size,
                              hipStream_t stream) {
    const float* x = (const float*)d_in[0];
    int* out = (int*)d_out;
    char* ws = (char*)d_ws;

    // Shared layout head
    constexpr size_t XNT_B = (size_t)BB * NN * DD * 4;          //  8,388,608
    constexpr size_t SQ_B  = (size_t)BB * NN * 4;               //    131,072
    float* xnT = (float*)ws;
    float* sq  = (float*)(ws + XNT_B);

    // New-path layout
    constexpr size_t BF_B  = (size_t)BB * NN * DD * 2;          //  4,194,304 each
    constexpr size_t OFF_PHI = XNT_B + SQ_B;
    constexpr size_t OFF_PLO = OFF_PHI + BF_B;
    constexpr size_t OFF_SHI = OFF_PLO + BF_B;
    constexpr size_t OFF_SLO = OFF_SHI + BF_B;
    constexpr size_t OFF_MIN = OFF_SLO + BF_B;
    constexpr size_t MIN_B   = (size_t)512 * BB * NN * 4;       // 67,108,864
    constexpr size_t NEED_NEW = OFF_MIN + MIN_B;                // 92,405,760

    if (ws_size >= NEED_NEW) {
        unsigned short* Phi = (unsigned short*)(ws + OFF_PHI);
        unsigned short* Plo = (unsigned short*)(ws + OFF_PLO);
        unsigned short* Shi = (unsigned short*)(ws + OFF_SHI);
        unsigned short* Slo = (unsigned short*)(ws + OFF_SLO);
        float* minbuf = (float*)(ws + OFF_MIN);

        knorm2_kernel<<<dim3(BB * NN / 256), dim3(256), 0, stream>>>(x, xnT, sq, Phi, Plo, Shi, Slo);
        kmin_kernel<<<dim3(BB * NN / 128, 4), dim3(256), 0, stream>>>(Shi, Slo, Phi, Plo, minbuf);
        ksel_kernel<<<dim3(BB * NN / 4), dim3(256), 0, stream>>>(xnT, sq, minbuf, out);
        return;
    }

    // Old verified path
    unsigned long long* cand = (unsigned long long*)(ws + XNT_B + SQ_B);
    const size_t base = XNT_B + SQ_B;
    const size_t need8 = base + (size_t)BB * NN * 8 * KK * 8;

    knorm_kernel<<<dim3(BB * NN / 256), dim3(256), 0, stream>>>(x, xnT, sq);
    if (ws_size >= need8) {
        kdist_kernel<8><<<dim3(BB * NN / 256, 8), dim3(256), 0, stream>>>(xnT, sq, cand);
        kmerge_kernel<8><<<dim3(BB * NN / 256), dim3(256), 0, stream>>>(cand, out);
    } else {
        kdist_kernel<4><<<dim3(BB * NN / 256, 4), dim3(256), 0, stream>>>(xnT, sq, cand);
        kmerge_kernel<4><<<dim3(BB * NN / 256), dim3(256), 0, stream>>>(cand, out);
    }
}

// Round 3
// 391.378 us; speedup vs baseline: 2.8712x; 1.2201x over previous
//
#include <hip/hip_runtime.h>

// Problem constants (fixed by setup_inputs): x (4, 64, 8192, 1) fp32, k=9, dilation=1
#define BB 4
#define DD 64
#define NN 8192
#define KK 9

// ---------------------------------------------------------------------------
// MFMA filter + exact rescan
//   K1 knorm2: normalize, emit fp32 xnT, sq, bf16 casts P=bf16(xn), S=bf16(-2xn)
//   K2 kmin:   pure-bf16 MFMA GEMM -> per-(row, 16-j-group) min of approx -2*dot,
//              staged in wave-private LDS, flushed as full-64B-line stores:
//              minbuf[row*512 + g], g = half*256 + tile
//   K3 ksel:   wave-per-row: theta = 9th-smallest group-min + 2.5e-2, ballot-
//              compacted candidate list, lane-balanced exact fp32 rescan,
//              cross-lane top-9 merge. Writes edge_index directly.
//   Filter error bound (rigorous): |bf16dot - dot| <= 2^-9*2*||-2x_j||*||x_i||
//     = 7.8e-3 (Cauchy-Schwarz, RNE rel-err 2^-9; fp32 MFMA accum negligible).
//     Completeness needs delta >= 2*err = 1.57e-2; delta = 2.5e-2 (60% margin).
//     >40-candidate overflow falls back to exact full scan (correct, rare).
// Fallback to the original verified path if ws_size is too small.
// ---------------------------------------------------------------------------

typedef __attribute__((ext_vector_type(8))) __bf16 bf16x8;   // 4 VGPR MFMA operand
typedef __attribute__((ext_vector_type(16))) float f32x16;   // 32x32 accumulator

__device__ __forceinline__ unsigned bf16rne(float f) {
    unsigned u = __float_as_uint(f);
    unsigned r = u + 0x7FFFu + ((u >> 16) & 1u);   // round-to-nearest-even
    return r >> 16;
}

__device__ __forceinline__ uint4 pack8(const unsigned* w) {
    return make_uint4(w[0] | (w[1] << 16), w[2] | (w[3] << 16),
                      w[4] | (w[5] << 16), w[6] | (w[7] << 16));
}

// ---------------- K1: normalize + fp32 pack + sq + bf16 casts -----------------
__global__ __launch_bounds__(256) void knorm2_kernel(const float* __restrict__ x,
                                                     float* __restrict__ xnT,
                                                     float* __restrict__ sq,
                                                     unsigned short* __restrict__ Phi,
                                                     unsigned short* __restrict__ Shi) {
    int t = blockIdx.x * 256 + threadIdx.x;      // row id 0..B*N-1
    int b = t >> 13;
    int n = t & (NN - 1);
    const float* xb = x + (size_t)b * DD * NN + n;
    float v[DD];
    float ss = 0.0f;
#pragma unroll
    for (int d = 0; d < DD; ++d) {
        v[d] = xb[(size_t)d * NN];
        ss = fmaf(v[d], v[d], ss);
    }
    float inv = 1.0f / fmaxf(sqrtf(ss), 1e-12f);
    float s2 = 0.0f;
#pragma unroll
    for (int d = 0; d < DD; ++d) {
        v[d] *= inv;
        s2 = fmaf(v[d], v[d], s2);
    }
    sq[t] = s2;
    float4* o4 = reinterpret_cast<float4*>(xnT + (size_t)t * DD);
#pragma unroll
    for (int d = 0; d < DD; d += 4) o4[d >> 2] = make_float4(v[d], v[d+1], v[d+2], v[d+3]);

    size_t base = (size_t)t * DD;
#pragma unroll
    for (int d0 = 0; d0 < DD; d0 += 8) {
        unsigned ph[8], sh[8];
#pragma unroll
        for (int e = 0; e < 8; ++e) {
            float f = v[d0 + e];
            ph[e] = bf16rne(f);
            sh[e] = bf16rne(-2.0f * f);              // exact scale before rounding
        }
        *reinterpret_cast<uint4*>(Phi + base + d0) = pack8(ph);
        *reinterpret_cast<uint4*>(Shi + base + d0) = pack8(sh);
    }
}

// ---------------- K2: MFMA min pass (pure bf16, LDS-staged writes) -----------
// Wave = 32 i-rows; block = 4 waves = 128 rows; grid (256 rowblocks, 4 jsplits).
// C/D col = lane&31 (HW-verified); per tile, lane (l31, half) produces the min
// over its 16 C-values = group g = half*256 + (goff+tt) for row i0+l31.
// Mins are staged in wave-private LDS [32][33] (pad -> 2 lanes/bank = free),
// flushed every 16 tiles as wave-wide float4 stores covering full aligned 64B
// lines (R1 post-mortem: scattered 16B stores caused 213MB partial-line write
// traffic at ~820 GB/s = the whole kernel time).
__global__ __launch_bounds__(256, 4) void kmin_kernel(const unsigned short* __restrict__ Shi,
                                                      const unsigned short* __restrict__ Phi,
                                                      float* __restrict__ minbuf) {
    __shared__ float stage[4][32][33];                  // 16.9 KB/block
    const int lane = threadIdx.x & 63;
    const int wave = threadIdx.x >> 6;
    const int l31 = lane & 31;
    const int half = lane >> 5;
    const int i0 = blockIdx.x * 128 + wave * 32;        // global i-row base
    const int b = i0 >> 13;
    const int jloc0 = blockIdx.y * (NN / 4);            // batch-local j start
    const int goff = jloc0 >> 5;                        // tile base (64 per split)
    const int row = i0 + l31;

    bf16x8 Bh[4];
    {
        const size_t ib = (size_t)row * DD + half * 8;
#pragma unroll
        for (int kc = 0; kc < 4; ++kc)
            Bh[kc] = *reinterpret_cast<const bf16x8*>(Phi + ib + kc * 16);
    }
    const size_t ja0 = ((size_t)b * NN + jloc0 + l31) * DD + half * 8;

#pragma unroll 1
    for (int f = 0; f < 4; ++f) {
#pragma unroll 4
        for (int u = 0; u < 16; ++u) {
            const int tt = f * 16 + u;
            const size_t ja = ja0 + (size_t)tt * 32 * DD;
            bf16x8 Ah[4];
#pragma unroll
            for (int kc = 0; kc < 4; ++kc)
                Ah[kc] = *reinterpret_cast<const bf16x8*>(Shi + ja + kc * 16);
            f32x16 c = {};
#pragma unroll
            for (int kc = 0; kc < 4; ++kc)
                c = __builtin_amdgcn_mfma_f32_32x32x16_bf16(Ah[kc], Bh[kc], c, 0, 0, 0);
            float m0 = fminf(fminf(c[0], c[1]), fminf(c[2], c[3]));
            float m1 = fminf(fminf(c[4], c[5]), fminf(c[6], c[7]));
            float m2 = fminf(fminf(c[8], c[9]), fminf(c[10], c[11]));
            float m3 = fminf(fminf(c[12], c[13]), fminf(c[14], c[15]));
            stage[wave][l31][half * 16 + u] = fminf(fminf(m0, m1), fminf(m2, m3));
        }
        // flush: wave-private LDS -> full-line global stores (no barrier needed)
        const int gbase = goff + f * 16;
#pragma unroll
        for (int it = 0; it < 4; ++it) {
            int idx = it * 64 + lane;
            int c4 = idx & 3;
            int hf = (idx >> 2) & 1;
            int r = idx >> 3;                            // 0..31
            const float* s = &stage[wave][r][hf * 16 + c4 * 4];
            float4 vv = make_float4(s[0], s[1], s[2], s[3]);
            *reinterpret_cast<float4*>(minbuf + (size_t)(i0 + r) * 512 +
                                       hf * 256 + gbase + c4 * 4) = vv;
        }
    }
}

// ---------------- K3: wave-per-row threshold + balanced exact rescan ---------
// One WAVE per row. Lane l owns groups l*8..l*8+7 (coalesced float4 loads).
// theta via 9 rounds of wave-min extraction (duplicate-consumption only raises
// theta -> safe). Candidates ballot-compacted to LDS, j-work round-robin over
// 64 lanes; exact fp32 dot identical to the original verified kernel.
__global__ __launch_bounds__(256) void ksel_kernel(const float* __restrict__ xnT,
                                                   const float* __restrict__ sq,
                                                   const float* __restrict__ minbuf,
                                                   int* __restrict__ out) {
    __shared__ unsigned short glist[4][40];
    const int lane = threadIdx.x & 63;
    const int wave = threadIdx.x >> 6;
    const int t = blockIdx.x * 4 + wave;                 // row id
    const int tu = __builtin_amdgcn_readfirstlane(t);    // wave-uniform row
    const int b = tu >> 13;
    const int n = tu & (NN - 1);

    float gm[8];
    {
        const float4* m4 = reinterpret_cast<const float4*>(minbuf + (size_t)tu * 512 + lane * 8);
        float4 a = m4[0], c = m4[1];
        gm[0] = a.x; gm[1] = a.y; gm[2] = a.z; gm[3] = a.w;
        gm[4] = c.x; gm[5] = c.y; gm[6] = c.z; gm[7] = c.w;
    }

    // theta: 9 rounds of wave-min extraction
    float w[8];
#pragma unroll
    for (int q = 0; q < 8; ++q) w[q] = gm[q];
    float th9 = 0.0f;
#pragma unroll
    for (int r = 0; r < KK; ++r) {
        float lm = fminf(fminf(fminf(w[0], w[1]), fminf(w[2], w[3])),
                         fminf(fminf(w[4], w[5]), fminf(w[6], w[7])));
        float wm = lm;
#pragma unroll
        for (int d = 1; d < 64; d <<= 1) wm = fminf(wm, __shfl_xor(wm, d));
#pragma unroll
        for (int q = 0; q < 8; ++q) if (w[q] <= wm) w[q] = __uint_as_float(0x7f800000u);
        th9 = wm;
    }
    const float theta = th9 + 2.5e-2f;   // delta >= 2*bf16-filter-err (1.57e-2)

    // ballot-compact candidate groups into LDS list
    int cnt = 0;
    unsigned short* gl = &glist[wave][0];
#pragma unroll
    for (int q = 0; q < 8; ++q) {
        bool c = gm[q] <= theta;
        unsigned long long mask = __ballot(c);
        int pos = cnt + __popcll(mask & ((1ULL << lane) - 1ULL));
        if (c && pos < 40) gl[pos] = (unsigned short)(lane * 8 + q);
        cnt += __popcll(mask);
    }
    __syncthreads();

    const float* __restrict__ Bb = xnT + (size_t)b * NN * DD;
    const float* __restrict__ sqb = sq + (size_t)b * NN;
    float ar[DD];
    {
        const float4* a4 = reinterpret_cast<const float4*>(xnT + (size_t)tu * DD);
#pragma unroll
        for (int d = 0; d < DD; d += 4) {
            float4 f = a4[d >> 2];
            ar[d] = f.x; ar[d + 1] = f.y; ar[d + 2] = f.z; ar[d + 3] = f.w;
        }
    }

    unsigned long long kd[KK];
#pragma unroll
    for (int m = 0; m < KK; ++m) kd[m] = ~0ULL;

    const bool ovf = (cnt > 40);
    const int total = ovf ? NN : cnt * 16;
#pragma unroll 1
    for (int idx = lane; idx < total; idx += 64) {
        int j;
        if (ovf) {
            j = idx;
        } else {
            int g = (int)gl[idx >> 4];
            int s4 = idx & 15;
            j = (g & 255) * 32 + ((s4 >> 2) * 8) + ((g >> 8) * 4) + (s4 & 3);
        }
        const float4* bc4 = reinterpret_cast<const float4*>(Bb + (size_t)j * DD);
        float a0 = 0.0f, a1 = 0.0f, a2 = 0.0f, a3 = 0.0f;
#pragma unroll
        for (int d4 = 0; d4 < DD / 4; ++d4) {
            float4 f = bc4[d4];
            a0 = fmaf(ar[4 * d4 + 0], f.x, a0);
            a1 = fmaf(ar[4 * d4 + 1], f.y, a1);
            a2 = fmaf(ar[4 * d4 + 2], f.z, a2);
            a3 = fmaf(ar[4 * d4 + 3], f.w, a3);
        }
        float dot = (a0 + a1) + (a2 + a3);
        float key = fmaf(-2.0f, dot, sqb[j]);
        unsigned ub = __float_as_uint(key);
        ub ^= (0x80000000u | (unsigned)((int)ub >> 31));
        unsigned long long cnd = ((unsigned long long)ub << 32) | (unsigned)j;
        if (cnd < kd[KK - 1]) {
#pragma unroll
            for (int m = 0; m < KK; ++m) {
                bool sw = cnd < kd[m];
                unsigned long long lo = sw ? cnd : kd[m];
                unsigned long long hi = sw ? kd[m] : cnd;
                kd[m] = lo;
                cnd = hi;
            }
        }
    }

    // cross-lane top-9 extraction; lane r keeps rank r
    unsigned long long kout = ~0ULL;
#pragma unroll
    for (int r = 0; r < KK; ++r) {
        unsigned long long c = kd[0];
        unsigned long long wm = c;
#pragma unroll
        for (int d = 1; d < 64; d <<= 1) {
            unsigned long long o = __shfl_xor(wm, d);
            wm = (o < wm) ? o : wm;
        }
        if (lane == r) kout = wm;
        if (c == wm) {
#pragma unroll
            for (int m = 0; m < KK - 1; ++m) kd[m] = kd[m + 1];
            kd[KK - 1] = ~0ULL;
        }
    }

    if (lane < KK) {
        out[(size_t)tu * KK + lane] = (int)(kout & 0xFFFFFFFFULL);
        out[(size_t)BB * NN * KK + (size_t)tu * KK + lane] = n;
    }
}

// ===========================================================================
// OLD PATH (verified fallback) -- unchanged
// ===========================================================================
__global__ __launch_bounds__(256) void knorm_kernel(const float* __restrict__ x,
                                                    float* __restrict__ xnT,
                                                    float* __restrict__ sq) {
    int t = blockIdx.x * 256 + threadIdx.x;
    int b = t >> 13;
    int n = t & (NN - 1);
    const float* xb = x + (size_t)b * DD * NN + n;
    float v[DD];
    float ss = 0.0f;
#pragma unroll
    for (int d = 0; d < DD; ++d) {
        v[d] = xb[(size_t)d * NN];
        ss = fmaf(v[d], v[d], ss);
    }
    float norm = sqrtf(ss);
    float inv = 1.0f / fmaxf(norm, 1e-12f);
    float s2 = 0.0f;
#pragma unroll
    for (int d = 0; d < DD; ++d) {
        float xv = v[d] * inv;
        v[d] = xv;
        s2 = fmaf(xv, xv, s2);
    }
    float4* o4 = reinterpret_cast<float4*>(xnT + (size_t)t * DD);
#pragma unroll
    for (int d = 0; d < DD; d += 4) {
        o4[d >> 2] = make_float4(v[d], v[d + 1], v[d + 2], v[d + 3]);
    }
    sq[t] = s2;
}

template <int S>
__global__ __launch_bounds__(256, 2) void kdist_kernel(const float* __restrict__ xnT,
                                                       const float* __restrict__ sq,
                                                       unsigned long long* __restrict__ cand) {
    const int rb = blockIdx.x;
    const int b = rb >> 5;
    const int nbase = (rb & 31) * 256;
    const int n = nbase + threadIdx.x;
    const int s = blockIdx.y;
    const int jcount = NN / S;
    const int j0 = s * jcount;
    const int j1 = j0 + jcount;

    const float* __restrict__ Bb = xnT + ((size_t)b * NN) * DD;
    const float* __restrict__ sqb = sq + (size_t)b * NN;

    float ar[DD];
    {
        const float4* a4 = reinterpret_cast<const float4*>(Bb + (size_t)n * DD);
#pragma unroll
        for (int d = 0; d < DD; d += 4) {
            float4 f = a4[d >> 2];
            ar[d] = f.x; ar[d + 1] = f.y; ar[d + 2] = f.z; ar[d + 3] = f.w;
        }
    }
#pragma unroll
    for (int d = 0; d < DD; ++d) {
        asm volatile("" : "+v"(ar[d]));
    }

    unsigned long long kd[KK];
#pragma unroll
    for (int m = 0; m < KK; ++m) kd[m] = ~0ULL;

#pragma unroll 2
    for (int j = j0; j < j1; ++j) {
        const float4* bc4 = reinterpret_cast<const float4*>(Bb + (size_t)j * DD);
        float a0 = 0.0f, a1 = 0.0f, a2 = 0.0f, a3 = 0.0f;
#pragma unroll
        for (int d4 = 0; d4 < DD / 4; ++d4) {
            float4 f = bc4[d4];
            a0 = fmaf(ar[4 * d4 + 0], f.x, a0);
            a1 = fmaf(ar[4 * d4 + 1], f.y, a1);
            a2 = fmaf(ar[4 * d4 + 2], f.z, a2);
            a3 = fmaf(ar[4 * d4 + 3], f.w, a3);
        }
        float dot = (a0 + a1) + (a2 + a3);
        float key = fmaf(-2.0f, dot, sqb[j]);
        unsigned int ub = __float_as_uint(key);
        ub ^= (0x80000000u | (unsigned int)((int)ub >> 31));
        unsigned long long cnd = ((unsigned long long)ub << 32) | (unsigned int)j;
        if (cnd < kd[KK - 1]) {
#pragma unroll
            for (int m = 0; m < KK; ++m) {
                bool sw = cnd < kd[m];
                unsigned long long lo = sw ? cnd : kd[m];
                unsigned long long hi = sw ? kd[m] : cnd;
                kd[m] = lo;
                cnd = hi;
            }
        }
    }

    unsigned long long* outc = cand + ((size_t)(b * NN + n) * S + s) * KK;
#pragma unroll
    for (int m = 0; m < KK; ++m) outc[m] = kd[m];
}

template <int S>
__global__ __launch_bounds__(256) void kmerge_kernel(const unsigned long long* __restrict__ cand,
                                                     int* __restrict__ out) {
    int t = blockIdx.x * 256 + threadIdx.x;
    const unsigned long long* c = cand + (size_t)t * (S * KK);
    unsigned long long kd[KK];
#pragma unroll
    for (int m = 0; m < KK; ++m) kd[m] = ~0ULL;
#pragma unroll
    for (int q = 0; q < S * KK; ++q) {
        unsigned long long cnd = c[q];
        if (cnd < kd[KK - 1]) {
#pragma unroll
            for (int m = 0; m < KK; ++m) {
                bool sw = cnd < kd[m];
                unsigned long long lo = sw ? cnd : kd[m];
                unsigned long long hi = sw ? kd[m] : cnd;
                kd[m] = lo;
                cnd = hi;
            }
        }
    }
    int n = t & (NN - 1);
    int* out0 = out + (size_t)t * KK;
    int* out1 = out + (size_t)BB * NN * KK + (size_t)t * KK;
#pragma unroll
    for (int m = 0; m < KK; ++m) {
        out0[m] = (int)(kd[m] & 0xFFFFFFFFULL);
        out1[m] = n;
    }
}

extern "C" void kernel_launch(void* const* d_in, const int* in_sizes, int n_in,
                              void* d_out, int out_size, void* d_ws, size_t ws_size,
                              hipStream_t stream) {
    const float* x = (const float*)d_in[0];
    int* out = (int*)d_out;
    char* ws = (char*)d_ws;

    // Shared layout head
    constexpr size_t XNT_B = (size_t)BB * NN * DD * 4;          //  8,388,608
    constexpr size_t SQ_B  = (size_t)BB * NN * 4;               //    131,072
    float* xnT = (float*)ws;
    float* sq  = (float*)(ws + XNT_B);

    // New-path layout (offsets kept from the verified R2 layout; Plo/Slo slots
    // are now unused but reserved so NEED_NEW is unchanged)
    constexpr size_t BF_B  = (size_t)BB * NN * DD * 2;          //  4,194,304 each
    constexpr size_t OFF_PHI = XNT_B + SQ_B;
    constexpr size_t OFF_PLO = OFF_PHI + BF_B;
    constexpr size_t OFF_SHI = OFF_PLO + BF_B;
    constexpr size_t OFF_SLO = OFF_SHI + BF_B;
    constexpr size_t OFF_MIN = OFF_SLO + BF_B;
    constexpr size_t MIN_B   = (size_t)512 * BB * NN * 4;       // 67,108,864
    constexpr size_t NEED_NEW = OFF_MIN + MIN_B;                // 92,405,760

    if (ws_size >= NEED_NEW) {
        unsigned short* Phi = (unsigned short*)(ws + OFF_PHI);
        unsigned short* Shi = (unsigned short*)(ws + OFF_SHI);
        float* minbuf = (float*)(ws + OFF_MIN);

        knorm2_kernel<<<dim3(BB * NN / 256), dim3(256), 0, stream>>>(x, xnT, sq, Phi, Shi);
        kmin_kernel<<<dim3(BB * NN / 128, 4), dim3(256), 0, stream>>>(Shi, Phi, minbuf);
        ksel_kernel<<<dim3(BB * NN / 4), dim3(256), 0, stream>>>(xnT, sq, minbuf, out);
        return;
    }

    // Old verified path
    unsigned long long* cand = (unsigned long long*)(ws + XNT_B + SQ_B);
    const size_t base = XNT_B + SQ_B;
    const size_t need8 = base + (size_t)BB * NN * 8 * KK * 8;

    knorm_kernel<<<dim3(BB * NN / 256), dim3(256), 0, stream>>>(x, xnT, sq);
    if (ws_size >= need8) {
        kdist_kernel<8><<<dim3(BB * NN / 256, 8), dim3(256), 0, stream>>>(xnT, sq, cand);
        kmerge_kernel<8><<<dim3(BB * NN / 256), dim3(256), 0, stream>>>(cand, out);
    } else {
        kdist_kernel<4><<<dim3(BB * NN / 256, 4), dim3(256), 0, stream>>>(xnT, sq, cand);
        kmerge_kernel<4><<<dim3(BB * NN / 256), dim3(256), 0, stream>>>(cand, out);
    }
}

// Round 4
// 362.691 us; speedup vs baseline: 3.0983x; 1.0791x over previous
//
#include <hip/hip_runtime.h>

// Problem constants (fixed by setup_inputs): x (4, 64, 8192, 1) fp32, k=9, dilation=1
#define BB 4
#define DD 64
#define NN 8192
#define KK 9

// ---------------------------------------------------------------------------
// MFMA filter + exact rescan
//   K1 knorm2: normalize, emit fp32 xnT, sq, fp16 casts P=fp16(xn), S=fp16(-2xn)
//   K2 kmin:   pure-fp16 MFMA GEMM -> per-(row, 16-j-group) min of approx -2*dot,
//              staged in wave-private LDS, flushed as full-64B-line stores:
//              minbuf[row*512 + g], g = half*256 + tile
//   K3 ksel:   wave-per-row: theta = 9th-smallest group-min + 8e-3, ballot-
//              compacted candidate list, lane-balanced exact fp32 rescan,
//              cross-lane top-9 merge. Writes edge_index directly.
//
//   Filter error bound (rigorous, replaces R3's bf16 analysis which used a
//   wrong 2^-9 rel-err — bf16 mantissa is 7 bits, rel-err 2^-8, so bf16
//   actually needed delta >= 3.1e-2 worst case):
//     fp16 RNE rel-err 2^-11; a = -2xn_j (||a||=2), b = xn_i (||b||=1).
//     |err| <= 2*2^-11*Sum|a||b| <= 2^-10*||a||*||b|| = 1.95e-3  (Cauchy-Schwarz)
//     + FTZ-subnormal worst case 6.1e-5*Sum|b| <= 4.9e-4
//     + sq_j-vs-const, fp32 rescan eval, MFMA f32-accum terms ~2e-5
//     => err <= 2.5e-3. Completeness needs delta >= 2*err = 5e-3.
//     delta = 8e-3 (60% margin). >40-candidate overflow -> exact full scan.
// Fallback to the original verified path if ws_size is too small.
// ---------------------------------------------------------------------------

typedef __attribute__((ext_vector_type(8))) _Float16 f16x8;  // 4 VGPR MFMA operand
typedef __attribute__((ext_vector_type(16))) float f32x16;   // 32x32 accumulator

__device__ __forceinline__ uint4 pack8(const unsigned* w) {
    return make_uint4(w[0] | (w[1] << 16), w[2] | (w[3] << 16),
                      w[4] | (w[5] << 16), w[6] | (w[7] << 16));
}

__device__ __forceinline__ float min3f(float a, float b, float c) {
    return fminf(fminf(a, b), c);            // clang fuses to v_min3_f32
}

// ---------------- K1: normalize + fp32 pack + sq + fp16 casts -----------------
__global__ __launch_bounds__(256) void knorm2_kernel(const float* __restrict__ x,
                                                     float* __restrict__ xnT,
                                                     float* __restrict__ sq,
                                                     unsigned short* __restrict__ Phi,
                                                     unsigned short* __restrict__ Shi) {
    int t = blockIdx.x * 256 + threadIdx.x;      // row id 0..B*N-1
    int b = t >> 13;
    int n = t & (NN - 1);
    const float* xb = x + (size_t)b * DD * NN + n;
    float v[DD];
    float ss = 0.0f;
#pragma unroll
    for (int d = 0; d < DD; ++d) {
        v[d] = xb[(size_t)d * NN];
        ss = fmaf(v[d], v[d], ss);
    }
    float inv = 1.0f / fmaxf(sqrtf(ss), 1e-12f);
    float s2 = 0.0f;
#pragma unroll
    for (int d = 0; d < DD; ++d) {
        v[d] *= inv;
        s2 = fmaf(v[d], v[d], s2);
    }
    sq[t] = s2;
    float4* o4 = reinterpret_cast<float4*>(xnT + (size_t)t * DD);
#pragma unroll
    for (int d = 0; d < DD; d += 4) o4[d >> 2] = make_float4(v[d], v[d+1], v[d+2], v[d+3]);

    size_t base = (size_t)t * DD;
#pragma unroll
    for (int d0 = 0; d0 < DD; d0 += 8) {
        unsigned ph[8], sh[8];
#pragma unroll
        for (int e = 0; e < 8; ++e) {
            float f = v[d0 + e];
            _Float16 hp = (_Float16)f;               // v_cvt_f16_f32 (RNE)
            _Float16 hs = (_Float16)(-2.0f * f);     // exact scale before rounding
            ph[e] = (unsigned)__builtin_bit_cast(unsigned short, hp);
            sh[e] = (unsigned)__builtin_bit_cast(unsigned short, hs);
        }
        *reinterpret_cast<uint4*>(Phi + base + d0) = pack8(ph);
        *reinterpret_cast<uint4*>(Shi + base + d0) = pack8(sh);
    }
}

// ---------------- K2: MFMA min pass (fp16, LDS-staged writes) ----------------
// Wave = 32 i-rows; block = 4 waves = 128 rows; grid (256 rowblocks, 4 jsplits).
// C/D col = lane&31 (HW-verified, dtype-independent); per tile, lane (l31,half)
// produces the min over its 16 C-values = group g = half*256 + (goff+tt) for
// row i0+l31. Mins staged in wave-private LDS [32][33] (pad -> 2 lanes/bank =
// free), flushed every 16 tiles as wave-wide float4 stores covering full
// aligned 64B lines (R2 post-mortem: scattered 16B stores = 213MB partial-line
// traffic = whole kernel time). min-tree via v_min3_f32 (8 ops vs 15).
__global__ __launch_bounds__(256, 4) void kmin_kernel(const unsigned short* __restrict__ Shi,
                                                      const unsigned short* __restrict__ Phi,
                                                      float* __restrict__ minbuf) {
    __shared__ float stage[4][32][33];                  // 16.9 KB/block
    const int lane = threadIdx.x & 63;
    const int wave = threadIdx.x >> 6;
    const int l31 = lane & 31;
    const int half = lane >> 5;
    const int i0 = blockIdx.x * 128 + wave * 32;        // global i-row base
    const int b = i0 >> 13;
    const int jloc0 = blockIdx.y * (NN / 4);            // batch-local j start
    const int goff = jloc0 >> 5;                        // tile base (64 per split)
    const int row = i0 + l31;

    f16x8 Bh[4];
    {
        const size_t ib = (size_t)row * DD + half * 8;
#pragma unroll
        for (int kc = 0; kc < 4; ++kc)
            Bh[kc] = *reinterpret_cast<const f16x8*>(Phi + ib + kc * 16);
    }
    const size_t ja0 = ((size_t)b * NN + jloc0 + l31) * DD + half * 8;

#pragma unroll 1
    for (int f = 0; f < 4; ++f) {
#pragma unroll 4
        for (int u = 0; u < 16; ++u) {
            const int tt = f * 16 + u;
            const size_t ja = ja0 + (size_t)tt * 32 * DD;
            f16x8 Ah[4];
#pragma unroll
            for (int kc = 0; kc < 4; ++kc)
                Ah[kc] = *reinterpret_cast<const f16x8*>(Shi + ja + kc * 16);
            f32x16 c = {};
#pragma unroll
            for (int kc = 0; kc < 4; ++kc)
                c = __builtin_amdgcn_mfma_f32_32x32x16_f16(Ah[kc], Bh[kc], c, 0, 0, 0);
            float t0 = min3f(c[0], c[1], c[2]);
            float t1 = min3f(c[3], c[4], c[5]);
            float t2 = min3f(c[6], c[7], c[8]);
            float t3 = min3f(c[9], c[10], c[11]);
            float t4 = min3f(c[12], c[13], c[14]);
            stage[wave][l31][half * 16 + u] =
                fminf(min3f(t0, t1, t2), min3f(t3, t4, c[15]));
        }
        // flush: wave-private LDS -> full-line global stores (no barrier needed)
        const int gbase = goff + f * 16;
#pragma unroll
        for (int it = 0; it < 4; ++it) {
            int idx = it * 64 + lane;
            int c4 = idx & 3;
            int hf = (idx >> 2) & 1;
            int r = idx >> 3;                            // 0..31
            const float* s = &stage[wave][r][hf * 16 + c4 * 4];
            float4 vv = make_float4(s[0], s[1], s[2], s[3]);
            *reinterpret_cast<float4*>(minbuf + (size_t)(i0 + r) * 512 +
                                       hf * 256 + gbase + c4 * 4) = vv;
        }
    }
}

// ---------------- K3: wave-per-row threshold + balanced exact rescan ---------
// One WAVE per row. Lane l owns groups l*8..l*8+7 (coalesced float4 loads).
// theta via 9 rounds of wave-min extraction (duplicate-consumption only raises
// theta -> safe). Candidates ballot-compacted to LDS, j-work round-robin over
// 64 lanes; exact fp32 dot identical to the original verified kernel.
__global__ __launch_bounds__(256) void ksel_kernel(const float* __restrict__ xnT,
                                                   const float* __restrict__ sq,
                                                   const float* __restrict__ minbuf,
                                                   int* __restrict__ out) {
    __shared__ unsigned short glist[4][40];
    const int lane = threadIdx.x & 63;
    const int wave = threadIdx.x >> 6;
    const int t = blockIdx.x * 4 + wave;                 // row id
    const int tu = __builtin_amdgcn_readfirstlane(t);    // wave-uniform row
    const int b = tu >> 13;
    const int n = tu & (NN - 1);

    float gm[8];
    {
        const float4* m4 = reinterpret_cast<const float4*>(minbuf + (size_t)tu * 512 + lane * 8);
        float4 a = m4[0], c = m4[1];
        gm[0] = a.x; gm[1] = a.y; gm[2] = a.z; gm[3] = a.w;
        gm[4] = c.x; gm[5] = c.y; gm[6] = c.z; gm[7] = c.w;
    }

    // theta: 9 rounds of wave-min extraction
    float w[8];
#pragma unroll
    for (int q = 0; q < 8; ++q) w[q] = gm[q];
    float th9 = 0.0f;
#pragma unroll
    for (int r = 0; r < KK; ++r) {
        float lm = fminf(fminf(fminf(w[0], w[1]), fminf(w[2], w[3])),
                         fminf(fminf(w[4], w[5]), fminf(w[6], w[7])));
        float wm = lm;
#pragma unroll
        for (int d = 1; d < 64; d <<= 1) wm = fminf(wm, __shfl_xor(wm, d));
#pragma unroll
        for (int q = 0; q < 8; ++q) if (w[q] <= wm) w[q] = __uint_as_float(0x7f800000u);
        th9 = wm;
    }
    const float theta = th9 + 8e-3f;   // delta >= 2*fp16-filter-err (5e-3), 60% margin

    // ballot-compact candidate groups into LDS list
    int cnt = 0;
    unsigned short* gl = &glist[wave][0];
#pragma unroll
    for (int q = 0; q < 8; ++q) {
        bool c = gm[q] <= theta;
        unsigned long long mask = __ballot(c);
        int pos = cnt + __popcll(mask & ((1ULL << lane) - 1ULL));
        if (c && pos < 40) gl[pos] = (unsigned short)(lane * 8 + q);
        cnt += __popcll(mask);
    }
    __syncthreads();

    const float* __restrict__ Bb = xnT + (size_t)b * NN * DD;
    const float* __restrict__ sqb = sq + (size_t)b * NN;
    float ar[DD];
    {
        const float4* a4 = reinterpret_cast<const float4*>(xnT + (size_t)tu * DD);
#pragma unroll
        for (int d = 0; d < DD; d += 4) {
            float4 f = a4[d >> 2];
            ar[d] = f.x; ar[d + 1] = f.y; ar[d + 2] = f.z; ar[d + 3] = f.w;
        }
    }

    unsigned long long kd[KK];
#pragma unroll
    for (int m = 0; m < KK; ++m) kd[m] = ~0ULL;

    const bool ovf = (cnt > 40);
    const int total = ovf ? NN : cnt * 16;
#pragma unroll 1
    for (int idx = lane; idx < total; idx += 64) {
        int j;
        if (ovf) {
            j = idx;
        } else {
            int g = (int)gl[idx >> 4];
            int s4 = idx & 15;
            j = (g & 255) * 32 + ((s4 >> 2) * 8) + ((g >> 8) * 4) + (s4 & 3);
        }
        const float4* bc4 = reinterpret_cast<const float4*>(Bb + (size_t)j * DD);
        float a0 = 0.0f, a1 = 0.0f, a2 = 0.0f, a3 = 0.0f;
#pragma unroll
        for (int d4 = 0; d4 < DD / 4; ++d4) {
            float4 f = bc4[d4];
            a0 = fmaf(ar[4 * d4 + 0], f.x, a0);
            a1 = fmaf(ar[4 * d4 + 1], f.y, a1);
            a2 = fmaf(ar[4 * d4 + 2], f.z, a2);
            a3 = fmaf(ar[4 * d4 + 3], f.w, a3);
        }
        float dot = (a0 + a1) + (a2 + a3);
        float key = fmaf(-2.0f, dot, sqb[j]);
        unsigned ub = __float_as_uint(key);
        ub ^= (0x80000000u | (unsigned)((int)ub >> 31));
        unsigned long long cnd = ((unsigned long long)ub << 32) | (unsigned)j;
        if (cnd < kd[KK - 1]) {
#pragma unroll
            for (int m = 0; m < KK; ++m) {
                bool sw = cnd < kd[m];
                unsigned long long lo = sw ? cnd : kd[m];
                unsigned long long hi = sw ? kd[m] : cnd;
                kd[m] = lo;
                cnd = hi;
            }
        }
    }

    // cross-lane top-9 extraction; lane r keeps rank r
    unsigned long long kout = ~0ULL;
#pragma unroll
    for (int r = 0; r < KK; ++r) {
        unsigned long long c = kd[0];
        unsigned long long wm = c;
#pragma unroll
        for (int d = 1; d < 64; d <<= 1) {
            unsigned long long o = __shfl_xor(wm, d);
            wm = (o < wm) ? o : wm;
        }
        if (lane == r) kout = wm;
        if (c == wm) {
#pragma unroll
            for (int m = 0; m < KK - 1; ++m) kd[m] = kd[m + 1];
            kd[KK - 1] = ~0ULL;
        }
    }

    if (lane < KK) {
        out[(size_t)tu * KK + lane] = (int)(kout & 0xFFFFFFFFULL);
        out[(size_t)BB * NN * KK + (size_t)tu * KK + lane] = n;
    }
}

// ===========================================================================
// OLD PATH (verified fallback) -- unchanged
// ===========================================================================
__global__ __launch_bounds__(256) void knorm_kernel(const float* __restrict__ x,
                                                    float* __restrict__ xnT,
                                                    float* __restrict__ sq) {
    int t = blockIdx.x * 256 + threadIdx.x;
    int b = t >> 13;
    int n = t & (NN - 1);
    const float* xb = x + (size_t)b * DD * NN + n;
    float v[DD];
    float ss = 0.0f;
#pragma unroll
    for (int d = 0; d < DD; ++d) {
        v[d] = xb[(size_t)d * NN];
        ss = fmaf(v[d], v[d], ss);
    }
    float norm = sqrtf(ss);
    float inv = 1.0f / fmaxf(norm, 1e-12f);
    float s2 = 0.0f;
#pragma unroll
    for (int d = 0; d < DD; ++d) {
        float xv = v[d] * inv;
        v[d] = xv;
        s2 = fmaf(xv, xv, s2);
    }
    float4* o4 = reinterpret_cast<float4*>(xnT + (size_t)t * DD);
#pragma unroll
    for (int d = 0; d < DD; d += 4) {
        o4[d >> 2] = make_float4(v[d], v[d + 1], v[d + 2], v[d + 3]);
    }
    sq[t] = s2;
}

template <int S>
__global__ __launch_bounds__(256, 2) void kdist_kernel(const float* __restrict__ xnT,
                                                       const float* __restrict__ sq,
                                                       unsigned long long* __restrict__ cand) {
    const int rb = blockIdx.x;
    const int b = rb >> 5;
    const int nbase = (rb & 31) * 256;
    const int n = nbase + threadIdx.x;
    const int s = blockIdx.y;
    const int jcount = NN / S;
    const int j0 = s * jcount;
    const int j1 = j0 + jcount;

    const float* __restrict__ Bb = xnT + ((size_t)b * NN) * DD;
    const float* __restrict__ sqb = sq + (size_t)b * NN;

    float ar[DD];
    {
        const float4* a4 = reinterpret_cast<const float4*>(Bb + (size_t)n * DD);
#pragma unroll
        for (int d = 0; d < DD; d += 4) {
            float4 f = a4[d >> 2];
            ar[d] = f.x; ar[d + 1] = f.y; ar[d + 2] = f.z; ar[d + 3] = f.w;
        }
    }
#pragma unroll
    for (int d = 0; d < DD; ++d) {
        asm volatile("" : "+v"(ar[d]));
    }

    unsigned long long kd[KK];
#pragma unroll
    for (int m = 0; m < KK; ++m) kd[m] = ~0ULL;

#pragma unroll 2
    for (int j = j0; j < j1; ++j) {
        const float4* bc4 = reinterpret_cast<const float4*>(Bb + (size_t)j * DD);
        float a0 = 0.0f, a1 = 0.0f, a2 = 0.0f, a3 = 0.0f;
#pragma unroll
        for (int d4 = 0; d4 < DD / 4; ++d4) {
            float4 f = bc4[d4];
            a0 = fmaf(ar[4 * d4 + 0], f.x, a0);
            a1 = fmaf(ar[4 * d4 + 1], f.y, a1);
            a2 = fmaf(ar[4 * d4 + 2], f.z, a2);
            a3 = fmaf(ar[4 * d4 + 3], f.w, a3);
        }
        float dot = (a0 + a1) + (a2 + a3);
        float key = fmaf(-2.0f, dot, sqb[j]);
        unsigned int ub = __float_as_uint(key);
        ub ^= (0x80000000u | (unsigned int)((int)ub >> 31));
        unsigned long long cnd = ((unsigned long long)ub << 32) | (unsigned int)j;
        if (cnd < kd[KK - 1]) {
#pragma unroll
            for (int m = 0; m < KK; ++m) {
                bool sw = cnd < kd[m];
                unsigned long long lo = sw ? cnd : kd[m];
                unsigned long long hi = sw ? kd[m] : cnd;
                kd[m] = lo;
                cnd = hi;
            }
        }
    }

    unsigned long long* outc = cand + ((size_t)(b * NN + n) * S + s) * KK;
#pragma unroll
    for (int m = 0; m < KK; ++m) outc[m] = kd[m];
}

template <int S>
__global__ __launch_bounds__(256) void kmerge_kernel(const unsigned long long* __restrict__ cand,
                                                     int* __restrict__ out) {
    int t = blockIdx.x * 256 + threadIdx.x;
    const unsigned long long* c = cand + (size_t)t * (S * KK);
    unsigned long long kd[KK];
#pragma unroll
    for (int m = 0; m < KK; ++m) kd[m] = ~0ULL;
#pragma unroll
    for (int q = 0; q < S * KK; ++q) {
        unsigned long long cnd = c[q];
        if (cnd < kd[KK - 1]) {
#pragma unroll
            for (int m = 0; m < KK; ++m) {
                bool sw = cnd < kd[m];
                unsigned long long lo = sw ? cnd : kd[m];
                unsigned long long hi = sw ? kd[m] : cnd;
                kd[m] = lo;
                cnd = hi;
            }
        }
    }
    int n = t & (NN - 1);
    int* out0 = out + (size_t)t * KK;
    int* out1 = out + (size_t)BB * NN * KK + (size_t)t * KK;
#pragma unroll
    for (int m = 0; m < KK; ++m) {
        out0[m] = (int)(kd[m] & 0xFFFFFFFFULL);
        out1[m] = n;
    }
}

extern "C" void kernel_launch(void* const* d_in, const int* in_sizes, int n_in,
                              void* d_out, int out_size, void* d_ws, size_t ws_size,
                              hipStream_t stream) {
    const float* x = (const float*)d_in[0];
    int* out = (int*)d_out;
    char* ws = (char*)d_ws;

    // Shared layout head
    constexpr size_t XNT_B = (size_t)BB * NN * DD * 4;          //  8,388,608
    constexpr size_t SQ_B  = (size_t)BB * NN * 4;               //    131,072
    float* xnT = (float*)ws;
    float* sq  = (float*)(ws + XNT_B);

    // New-path layout (offsets kept from the verified R2 layout; Plo/Slo slots
    // are unused but reserved so NEED_NEW is unchanged)
    constexpr size_t BF_B  = (size_t)BB * NN * DD * 2;          //  4,194,304 each
    constexpr size_t OFF_PHI = XNT_B + SQ_B;
    constexpr size_t OFF_PLO = OFF_PHI + BF_B;
    constexpr size_t OFF_SHI = OFF_PLO + BF_B;
    constexpr size_t OFF_SLO = OFF_SHI + BF_B;
    constexpr size_t OFF_MIN = OFF_SLO + BF_B;
    constexpr size_t MIN_B   = (size_t)512 * BB * NN * 4;       // 67,108,864
    constexpr size_t NEED_NEW = OFF_MIN + MIN_B;                // 92,405,760

    if (ws_size >= NEED_NEW) {
        unsigned short* Phi = (unsigned short*)(ws + OFF_PHI);
        unsigned short* Shi = (unsigned short*)(ws + OFF_SHI);
        float* minbuf = (float*)(ws + OFF_MIN);

        knorm2_kernel<<<dim3(BB * NN / 256), dim3(256), 0, stream>>>(x, xnT, sq, Phi, Shi);
        kmin_kernel<<<dim3(BB * NN / 128, 4), dim3(256), 0, stream>>>(Shi, Phi, minbuf);
        ksel_kernel<<<dim3(BB * NN / 4), dim3(256), 0, stream>>>(xnT, sq, minbuf, out);
        return;
    }

    // Old verified path
    unsigned long long* cand = (unsigned long long*)(ws + XNT_B + SQ_B);
    const size_t base = XNT_B + SQ_B;
    const size_t need8 = base + (size_t)BB * NN * 8 * KK * 8;

    knorm_kernel<<<dim3(BB * NN / 256), dim3(256), 0, stream>>>(x, xnT, sq);
    if (ws_size >= need8) {
        kdist_kernel<8><<<dim3(BB * NN / 256, 8), dim3(256), 0, stream>>>(xnT, sq, cand);
        kmerge_kernel<8><<<dim3(BB * NN / 256), dim3(256), 0, stream>>>(cand, out);
    } else {
        kdist_kernel<4><<<dim3(BB * NN / 256, 4), dim3(256), 0, stream>>>(xnT, sq, cand);
        kmerge_kernel<4><<<dim3(BB * NN / 256), dim3(256), 0, stream>>>(cand, out);
    }
}

// Round 6
// 357.567 us; speedup vs baseline: 3.1427x; 1.0143x over previous
//
#include <hip/hip_runtime.h>

// Problem constants (fixed by setup_inputs): x (4, 64, 8192, 1) fp32, k=9, dilation=1
#define BB 4
#define DD 64
#define NN 8192
#define KK 9

// ---------------------------------------------------------------------------
// MFMA filter + exact rescan
//   K1 knorm2: normalize, emit fp32 xnT, sq, fp16 casts P=fp16(xn), S=fp16(-2xn)
//   K2 kmin:   pure-fp16 MFMA GEMM -> per-(row, 16-j-group) min of approx -2*dot
//              (NOTE: minbuf values are in "-2*dot" UNITS, no sq_j term),
//              staged in wave-private LDS, flushed as full-64B-line stores:
//              minbuf[row*512 + g], g = half*256 + tile
//   K3 ksel:   wave-per-row:
//     th9p  = 9th-smallest LANE-min (one 21-stage bitonic of 64 lane-mins)
//     theta = th9p + 8e-3 group window (minbuf units, R3/R4-proven logic)
//     kappa2= th9p + 4e-3 survivor cutoff applied to -2*dot  [R5 POST-MORTEM:
//             R5 compared kappa against the EXACT key sq_j-2dot (~ +1 offset
//             in units) -> zero survivors -> -1 indices. Fix: compare in
//             minbuf units: -2dot(j) <= th9p+err+dSq for any top-9 j, since
//             v9 <= th9p + err + sq_max and -2dot = exact - sq_j.
//             err<=2.5e-3 (fp16 bound below), dSq<=1e-4 -> 2.6e-3 needed,
//             4e-3 used. Ordering among survivors still uses the byte-exact
//             u64 (key,j) -> reference tie-breaking preserved.]
//     top-9 = ONE 21-stage u64 bitonic of <=64 survivors; lane r = rank r.
//     Fallbacks: cnt>40 groups -> exact full scan; S>64 -> per-lane kd[9].
//
//   fp16 filter error bound (rigorous): RNE rel-err 2^-11; a=-2xn_j (||a||=2),
//   b=xn_i (||b||=1): |err| <= 2*2^-11*||a||*||b|| = 1.95e-3 (Cauchy-Schwarz)
//   + FTZ-subnormal 4.9e-4 + fp32/MFMA-accum ~2e-5 => err <= 2.5e-3.
// Fallback to the original verified path if ws_size is too small.
// ---------------------------------------------------------------------------

typedef __attribute__((ext_vector_type(8))) _Float16 f16x8;  // 4 VGPR MFMA operand
typedef __attribute__((ext_vector_type(16))) float f32x16;   // 32x32 accumulator

__device__ __forceinline__ uint4 pack8(const unsigned* w) {
    return make_uint4(w[0] | (w[1] << 16), w[2] | (w[3] << 16),
                      w[4] | (w[5] << 16), w[6] | (w[7] << 16));
}

__device__ __forceinline__ float min3f(float a, float b, float c) {
    return fminf(fminf(a, b), c);            // clang fuses to v_min3_f32
}

// ---------------- K1: normalize + fp32 pack + sq + fp16 casts -----------------
__global__ __launch_bounds__(256) void knorm2_kernel(const float* __restrict__ x,
                                                     float* __restrict__ xnT,
                                                     float* __restrict__ sq,
                                                     unsigned short* __restrict__ Phi,
                                                     unsigned short* __restrict__ Shi) {
    int t = blockIdx.x * 256 + threadIdx.x;      // row id 0..B*N-1
    int b = t >> 13;
    int n = t & (NN - 1);
    const float* xb = x + (size_t)b * DD * NN + n;
    float v[DD];
    float ss = 0.0f;
#pragma unroll
    for (int d = 0; d < DD; ++d) {
        v[d] = xb[(size_t)d * NN];
        ss = fmaf(v[d], v[d], ss);
    }
    float inv = 1.0f / fmaxf(sqrtf(ss), 1e-12f);
    float s2 = 0.0f;
#pragma unroll
    for (int d = 0; d < DD; ++d) {
        v[d] *= inv;
        s2 = fmaf(v[d], v[d], s2);
    }
    sq[t] = s2;
    float4* o4 = reinterpret_cast<float4*>(xnT + (size_t)t * DD);
#pragma unroll
    for (int d = 0; d < DD; d += 4) o4[d >> 2] = make_float4(v[d], v[d+1], v[d+2], v[d+3]);

    size_t base = (size_t)t * DD;
#pragma unroll
    for (int d0 = 0; d0 < DD; d0 += 8) {
        unsigned ph[8], sh[8];
#pragma unroll
        for (int e = 0; e < 8; ++e) {
            float f = v[d0 + e];
            _Float16 hp = (_Float16)f;               // v_cvt_f16_f32 (RNE)
            _Float16 hs = (_Float16)(-2.0f * f);     // exact scale before rounding
            ph[e] = (unsigned)__builtin_bit_cast(unsigned short, hp);
            sh[e] = (unsigned)__builtin_bit_cast(unsigned short, hs);
        }
        *reinterpret_cast<uint4*>(Phi + base + d0) = pack8(ph);
        *reinterpret_cast<uint4*>(Shi + base + d0) = pack8(sh);
    }
}

// ---------------- K2: MFMA min pass (fp16, LDS-staged writes) ----------------
// Wave = 32 i-rows; block = 4 waves = 128 rows; grid (256 rowblocks, 4 jsplits).
// C/D col = lane&31 (HW-verified, dtype-independent); per tile, lane (l31,half)
// produces the min over its 16 C-values = group g = half*256 + (goff+tt) for
// row i0+l31. Mins staged in wave-private LDS [32][33] (pad -> 2 lanes/bank =
// free), flushed every 16 tiles as wave-wide float4 stores covering full
// aligned 64B lines (R2 post-mortem: scattered 16B stores = 213MB partial-line
// traffic = whole kernel time). min-tree via v_min3_f32 (8 ops vs 15).
__global__ __launch_bounds__(256, 4) void kmin_kernel(const unsigned short* __restrict__ Shi,
                                                      const unsigned short* __restrict__ Phi,
                                                      float* __restrict__ minbuf) {
    __shared__ float stage[4][32][33];                  // 16.9 KB/block
    const int lane = threadIdx.x & 63;
    const int wave = threadIdx.x >> 6;
    const int l31 = lane & 31;
    const int half = lane >> 5;
    const int i0 = blockIdx.x * 128 + wave * 32;        // global i-row base
    const int b = i0 >> 13;
    const int jloc0 = blockIdx.y * (NN / 4);            // batch-local j start
    const int goff = jloc0 >> 5;                        // tile base (64 per split)
    const int row = i0 + l31;

    f16x8 Bh[4];
    {
        const size_t ib = (size_t)row * DD + half * 8;
#pragma unroll
        for (int kc = 0; kc < 4; ++kc)
            Bh[kc] = *reinterpret_cast<const f16x8*>(Phi + ib + kc * 16);
    }
    const size_t ja0 = ((size_t)b * NN + jloc0 + l31) * DD + half * 8;

#pragma unroll 1
    for (int f = 0; f < 4; ++f) {
#pragma unroll 4
        for (int u = 0; u < 16; ++u) {
            const int tt = f * 16 + u;
            const size_t ja = ja0 + (size_t)tt * 32 * DD;
            f16x8 Ah[4];
#pragma unroll
            for (int kc = 0; kc < 4; ++kc)
                Ah[kc] = *reinterpret_cast<const f16x8*>(Shi + ja + kc * 16);
            f32x16 c = {};
#pragma unroll
            for (int kc = 0; kc < 4; ++kc)
                c = __builtin_amdgcn_mfma_f32_32x32x16_f16(Ah[kc], Bh[kc], c, 0, 0, 0);
            float t0 = min3f(c[0], c[1], c[2]);
            float t1 = min3f(c[3], c[4], c[5]);
            float t2 = min3f(c[6], c[7], c[8]);
            float t3 = min3f(c[9], c[10], c[11]);
            float t4 = min3f(c[12], c[13], c[14]);
            stage[wave][l31][half * 16 + u] =
                fminf(min3f(t0, t1, t2), min3f(t3, t4, c[15]));
        }
        // flush: wave-private LDS -> full-line global stores (no barrier needed)
        const int gbase = goff + f * 16;
#pragma unroll
        for (int it = 0; it < 4; ++it) {
            int idx = it * 64 + lane;
            int c4 = idx & 3;
            int hf = (idx >> 2) & 1;
            int r = idx >> 3;                            // 0..31
            const float* s = &stage[wave][r][hf * 16 + c4 * 4];
            float4 vv = make_float4(s[0], s[1], s[2], s[3]);
            *reinterpret_cast<float4*>(minbuf + (size_t)(i0 + r) * 512 +
                                       hf * 256 + gbase + c4 * 4) = vv;
        }
    }
}

// ---------------- K3: wave-per-row, bitonic theta + survivor bitonic top-9 ---
__global__ __launch_bounds__(256) void ksel_kernel(const float* __restrict__ xnT,
                                                   const float* __restrict__ sq,
                                                   const float* __restrict__ minbuf,
                                                   int* __restrict__ out) {
    __shared__ unsigned short glist[4][40];
    __shared__ unsigned long long surv[4][64];
    const int lane = threadIdx.x & 63;
    const int wave = threadIdx.x >> 6;
    const int t = blockIdx.x * 4 + wave;                 // row id
    const int tu = __builtin_amdgcn_readfirstlane(t);    // wave-uniform row
    const int b = tu >> 13;
    const int n = tu & (NN - 1);

    // lane's 8 group-mins (coalesced: 2KB contiguous per wave)
    float gm[8];
    {
        const float4* m4 = reinterpret_cast<const float4*>(minbuf + (size_t)tu * 512 + lane * 8);
        float4 a = m4[0], c = m4[1];
        gm[0] = a.x; gm[1] = a.y; gm[2] = a.z; gm[3] = a.w;
        gm[4] = c.x; gm[5] = c.y; gm[6] = c.z; gm[7] = c.w;
    }

    // th9p: bitonic-sort the 64 lane-mins (ascending); lane 8 holds 9th-smallest
    float sv = fminf(min3f(gm[0], gm[1], gm[2]),
                     fminf(min3f(gm[3], gm[4], gm[5]), fminf(gm[6], gm[7])));
#pragma unroll
    for (int k = 2; k <= 64; k <<= 1) {
#pragma unroll
        for (int jj = k >> 1; jj >= 1; jj >>= 1) {
            float o = __shfl_xor(sv, jj);
            bool keepMin = (((lane & jj) == 0) == ((lane & k) == 0));
            sv = keepMin ? fminf(sv, o) : fmaxf(sv, o);
        }
    }
    const float th9p = __shfl(sv, 8);
    const float theta = th9p + 8e-3f;     // group window (minbuf units)
    const float kappa2F = th9p + 4e-3f;   // survivor cutoff on -2*dot (minbuf units)

    // ballot-compact candidate groups into wave-private LDS list
    int cnt = 0;
    unsigned short* gl = &glist[wave][0];
#pragma unroll
    for (int q = 0; q < 8; ++q) {
        bool c = gm[q] <= theta;
        unsigned long long mask = __ballot(c);
        int pos = cnt + __popcll(mask & ((1ULL << lane) - 1ULL));
        if (c && pos < 40) gl[pos] = (unsigned short)(lane * 8 + q);
        cnt += (int)__popcll(mask);
    }
    __syncthreads();

    // row vector (wave-uniform address -> scalar/SGPR loads)
    const float* __restrict__ Bb = xnT + (size_t)b * NN * DD;
    const float* __restrict__ sqb = sq + (size_t)b * NN;
    float ar[DD];
    {
        const float4* a4 = reinterpret_cast<const float4*>(xnT + (size_t)tu * DD);
#pragma unroll
        for (int d = 0; d < DD; d += 4) {
            float4 f = a4[d >> 2];
            ar[d] = f.x; ar[d + 1] = f.y; ar[d + 2] = f.z; ar[d + 3] = f.w;
        }
    }

    // exact fp32 rescan; survivors (-2dot <= kappa2) ballot-compact to LDS.
    const bool ovf = (cnt > 40);
    const int total = ovf ? NN : cnt * 16;
    const int nIt = (total + 63) >> 6;
    int S = 0;
#pragma unroll 1
    for (int m = 0; m < nIt; ++m) {
        const int idx = m * 64 + lane;
        const bool act = idx < total;
        unsigned long long cnd = ~0ULL;
        float m2dot = __uint_as_float(0x7f800000u);      // +inf for inactive
        if (act) {
            int j;
            if (ovf) {
                j = idx;
            } else {
                int g = (int)gl[idx >> 4];
                int s4 = idx & 15;
                j = (g & 255) * 32 + ((s4 >> 2) * 8) + ((g >> 8) * 4) + (s4 & 3);
            }
            const float4* bc4 = reinterpret_cast<const float4*>(Bb + (size_t)j * DD);
            float a0 = 0.0f, a1 = 0.0f, a2 = 0.0f, a3 = 0.0f;
#pragma unroll
            for (int d4 = 0; d4 < DD / 4; ++d4) {
                float4 f = bc4[d4];
                a0 = fmaf(ar[4 * d4 + 0], f.x, a0);
                a1 = fmaf(ar[4 * d4 + 1], f.y, a1);
                a2 = fmaf(ar[4 * d4 + 2], f.z, a2);
                a3 = fmaf(ar[4 * d4 + 3], f.w, a3);
            }
            float dot = (a0 + a1) + (a2 + a3);
            m2dot = -2.0f * dot;                         // exact in fp32
            float key = fmaf(-2.0f, dot, sqb[j]);        // byte-identical ordering key
            unsigned ub = __float_as_uint(key);
            ub ^= (0x80000000u | (unsigned)((int)ub >> 31));
            cnd = ((unsigned long long)ub << 32) | (unsigned)j;
        }
        bool pass = act && (m2dot <= kappa2F);
        unsigned long long mask = __ballot(pass);
        int pos = S + __popcll(mask & ((1ULL << lane) - 1ULL));
        if (pass && pos < 64) surv[wave][pos] = cnd;
        S += (int)__popcll(mask);
    }
    __syncthreads();

    unsigned long long kout = ~0ULL;
    if (S <= 64) {
        // ONE bitonic sort of survivors across lanes; lane r ends with rank r.
        unsigned long long v = (lane < S) ? surv[wave][lane] : ~0ULL;
#pragma unroll
        for (int k = 2; k <= 64; k <<= 1) {
#pragma unroll
            for (int jj = k >> 1; jj >= 1; jj >>= 1) {
                unsigned long long o = __shfl_xor(v, jj);
                bool keepMin = (((lane & jj) == 0) == ((lane & k) == 0));
                bool less = o < v;
                unsigned long long mn = less ? o : v;
                unsigned long long mx = less ? v : o;
                v = keepMin ? mn : mx;
            }
        }
        kout = v;
    } else {
        // rare: exact per-lane kd[9] + 9-round butterfly over the candidate set
        unsigned long long kd[KK];
#pragma unroll
        for (int m = 0; m < KK; ++m) kd[m] = ~0ULL;
#pragma unroll 1
        for (int m = 0; m < nIt; ++m) {
            const int idx = m * 64 + lane;
            if (idx >= total) continue;
            int j;
            if (ovf) {
                j = idx;
            } else {
                int g = (int)gl[idx >> 4];
                int s4 = idx & 15;
                j = (g & 255) * 32 + ((s4 >> 2) * 8) + ((g >> 8) * 4) + (s4 & 3);
            }
            const float4* bc4 = reinterpret_cast<const float4*>(Bb + (size_t)j * DD);
            float a0 = 0.0f, a1 = 0.0f, a2 = 0.0f, a3 = 0.0f;
#pragma unroll
            for (int d4 = 0; d4 < DD / 4; ++d4) {
                float4 f = bc4[d4];
                a0 = fmaf(ar[4 * d4 + 0], f.x, a0);
                a1 = fmaf(ar[4 * d4 + 1], f.y, a1);
                a2 = fmaf(ar[4 * d4 + 2], f.z, a2);
                a3 = fmaf(ar[4 * d4 + 3], f.w, a3);
            }
            float dot = (a0 + a1) + (a2 + a3);
            float key = fmaf(-2.0f, dot, sqb[j]);
            unsigned ub = __float_as_uint(key);
            ub ^= (0x80000000u | (unsigned)((int)ub >> 31));
            unsigned long long cnd = ((unsigned long long)ub << 32) | (unsigned)j;
            if (cnd < kd[KK - 1]) {
#pragma unroll
                for (int m2 = 0; m2 < KK; ++m2) {
                    bool sw = cnd < kd[m2];
                    unsigned long long lo = sw ? cnd : kd[m2];
                    unsigned long long hi = sw ? kd[m2] : cnd;
                    kd[m2] = lo;
                    cnd = hi;
                }
            }
        }
#pragma unroll
        for (int r = 0; r < KK; ++r) {
            unsigned long long c = kd[0];
            unsigned long long wm = c;
#pragma unroll
            for (int d = 1; d < 64; d <<= 1) {
                unsigned long long o = __shfl_xor(wm, d);
                wm = (o < wm) ? o : wm;
            }
            if (lane == r) kout = wm;
            if (c == wm) {
#pragma unroll
                for (int m2 = 0; m2 < KK - 1; ++m2) kd[m2] = kd[m2 + 1];
                kd[KK - 1] = ~0ULL;
            }
        }
    }

    if (lane < KK) {
        out[(size_t)tu * KK + lane] = (int)(kout & 0xFFFFFFFFULL);
        out[(size_t)BB * NN * KK + (size_t)tu * KK + lane] = n;
    }
}

// ===========================================================================
// OLD PATH (verified fallback) -- unchanged
// ===========================================================================
__global__ __launch_bounds__(256) void knorm_kernel(const float* __restrict__ x,
                                                    float* __restrict__ xnT,
                                                    float* __restrict__ sq) {
    int t = blockIdx.x * 256 + threadIdx.x;
    int b = t >> 13;
    int n = t & (NN - 1);
    const float* xb = x + (size_t)b * DD * NN + n;
    float v[DD];
    float ss = 0.0f;
#pragma unroll
    for (int d = 0; d < DD; ++d) {
        v[d] = xb[(size_t)d * NN];
        ss = fmaf(v[d], v[d], ss);
    }
    float norm = sqrtf(ss);
    float inv = 1.0f / fmaxf(norm, 1e-12f);
    float s2 = 0.0f;
#pragma unroll
    for (int d = 0; d < DD; ++d) {
        float xv = v[d] * inv;
        v[d] = xv;
        s2 = fmaf(xv, xv, s2);
    }
    float4* o4 = reinterpret_cast<float4*>(xnT + (size_t)t * DD);
#pragma unroll
    for (int d = 0; d < DD; d += 4) {
        o4[d >> 2] = make_float4(v[d], v[d + 1], v[d + 2], v[d + 3]);
    }
    sq[t] = s2;
}

template <int S>
__global__ __launch_bounds__(256, 2) void kdist_kernel(const float* __restrict__ xnT,
                                                       const float* __restrict__ sq,
                                                       unsigned long long* __restrict__ cand) {
    const int rb = blockIdx.x;
    const int b = rb >> 5;
    const int nbase = (rb & 31) * 256;
    const int n = nbase + threadIdx.x;
    const int s = blockIdx.y;
    const int jcount = NN / S;
    const int j0 = s * jcount;
    const int j1 = j0 + jcount;

    const float* __restrict__ Bb = xnT + ((size_t)b * NN) * DD;
    const float* __restrict__ sqb = sq + (size_t)b * NN;

    float ar[DD];
    {
        const float4* a4 = reinterpret_cast<const float4*>(Bb + (size_t)n * DD);
#pragma unroll
        for (int d = 0; d < DD; d += 4) {
            float4 f = a4[d >> 2];
            ar[d] = f.x; ar[d + 1] = f.y; ar[d + 2] = f.z; ar[d + 3] = f.w;
        }
    }
#pragma unroll
    for (int d = 0; d < DD; ++d) {
        asm volatile("" : "+v"(ar[d]));
    }

    unsigned long long kd[KK];
#pragma unroll
    for (int m = 0; m < KK; ++m) kd[m] = ~0ULL;

#pragma unroll 2
    for (int j = j0; j < j1; ++j) {
        const float4* bc4 = reinterpret_cast<const float4*>(Bb + (size_t)j * DD);
        float a0 = 0.0f, a1 = 0.0f, a2 = 0.0f, a3 = 0.0f;
#pragma unroll
        for (int d4 = 0; d4 < DD / 4; ++d4) {
            float4 f = bc4[d4];
            a0 = fmaf(ar[4 * d4 + 0], f.x, a0);
            a1 = fmaf(ar[4 * d4 + 1], f.y, a1);
            a2 = fmaf(ar[4 * d4 + 2], f.z, a2);
            a3 = fmaf(ar[4 * d4 + 3], f.w, a3);
        }
        float dot = (a0 + a1) + (a2 + a3);
        float key = fmaf(-2.0f, dot, sqb[j]);
        unsigned int ub = __float_as_uint(key);
        ub ^= (0x80000000u | (unsigned int)((int)ub >> 31));
        unsigned long long cnd = ((unsigned long long)ub << 32) | (unsigned int)j;
        if (cnd < kd[KK - 1]) {
#pragma unroll
            for (int m = 0; m < KK; ++m) {
                bool sw = cnd < kd[m];
                unsigned long long lo = sw ? cnd : kd[m];
                unsigned long long hi = sw ? kd[m] : cnd;
                kd[m] = lo;
                cnd = hi;
            }
        }
    }

    unsigned long long* outc = cand + ((size_t)(b * NN + n) * S + s) * KK;
#pragma unroll
    for (int m = 0; m < KK; ++m) outc[m] = kd[m];
}

template <int S>
__global__ __launch_bounds__(256) void kmerge_kernel(const unsigned long long* __restrict__ cand,
                                                     int* __restrict__ out) {
    int t = blockIdx.x * 256 + threadIdx.x;
    const unsigned long long* c = cand + (size_t)t * (S * KK);
    unsigned long long kd[KK];
#pragma unroll
    for (int m = 0; m < KK; ++m) kd[m] = ~0ULL;
#pragma unroll
    for (int q = 0; q < S * KK; ++q) {
        unsigned long long cnd = c[q];
        if (cnd < kd[KK - 1]) {
#pragma unroll
            for (int m = 0; m < KK; ++m) {
                bool sw = cnd < kd[m];
                unsigned long long lo = sw ? cnd : kd[m];
                unsigned long long hi = sw ? kd[m] : cnd;
                kd[m] = lo;
                cnd = hi;
            }
        }
    }
    int n = t & (NN - 1);
    int* out0 = out + (size_t)t * KK;
    int* out1 = out + (size_t)BB * NN * KK + (size_t)t * KK;
#pragma unroll
    for (int m = 0; m < KK; ++m) {
        out0[m] = (int)(kd[m] & 0xFFFFFFFFULL);
        out1[m] = n;
    }
}

extern "C" void kernel_launch(void* const* d_in, const int* in_sizes, int n_in,
                              void* d_out, int out_size, void* d_ws, size_t ws_size,
                              hipStream_t stream) {
    const float* x = (const float*)d_in[0];
    int* out = (int*)d_out;
    char* ws = (char*)d_ws;

    // Shared layout head
    constexpr size_t XNT_B = (size_t)BB * NN * DD * 4;          //  8,388,608
    constexpr size_t SQ_B  = (size_t)BB * NN * 4;               //    131,072
    float* xnT = (float*)ws;
    float* sq  = (float*)(ws + XNT_B);

    // New-path layout (offsets kept from the verified R2 layout; Plo/Slo slots
    // are unused but reserved so NEED_NEW is unchanged)
    constexpr size_t BF_B  = (size_t)BB * NN * DD * 2;          //  4,194,304 each
    constexpr size_t OFF_PHI = XNT_B + SQ_B;
    constexpr size_t OFF_PLO = OFF_PHI + BF_B;
    constexpr size_t OFF_SHI = OFF_PLO + BF_B;
    constexpr size_t OFF_SLO = OFF_SHI + BF_B;
    constexpr size_t OFF_MIN = OFF_SLO + BF_B;
    constexpr size_t MIN_B   = (size_t)512 * BB * NN * 4;       // 67,108,864
    constexpr size_t NEED_NEW = OFF_MIN + MIN_B;                // 92,405,760

    if (ws_size >= NEED_NEW) {
        unsigned short* Phi = (unsigned short*)(ws + OFF_PHI);
        unsigned short* Shi = (unsigned short*)(ws + OFF_SHI);
        float* minbuf = (float*)(ws + OFF_MIN);

        knorm2_kernel<<<dim3(BB * NN / 256), dim3(256), 0, stream>>>(x, xnT, sq, Phi, Shi);
        kmin_kernel<<<dim3(BB * NN / 128, 4), dim3(256), 0, stream>>>(Shi, Phi, minbuf);
        ksel_kernel<<<dim3(BB * NN / 4), dim3(256), 0, stream>>>(xnT, sq, minbuf, out);
        return;
    }

    // Old verified path
    unsigned long long* cand = (unsigned long long*)(ws + XNT_B + SQ_B);
    const size_t base = XNT_B + SQ_B;
    const size_t need8 = base + (size_t)BB * NN * 8 * KK * 8;

    knorm_kernel<<<dim3(BB * NN / 256), dim3(256), 0, stream>>>(x, xnT, sq);
    if (ws_size >= need8) {
        kdist_kernel<8><<<dim3(BB * NN / 256, 8), dim3(256), 0, stream>>>(xnT, sq, cand);
        kmerge_kernel<8><<<dim3(BB * NN / 256), dim3(256), 0, stream>>>(cand, out);
    } else {
        kdist_kernel<4><<<dim3(BB * NN / 256, 4), dim3(256), 0, stream>>>(xnT, sq, cand);
        kmerge_kernel<4><<<dim3(BB * NN / 256), dim3(256), 0, stream>>>(cand, out);
    }
}